// Round 9
// baseline (240.353 us; speedup 1.0000x reference)
//
#include <hip/hip_runtime.h>

// Problem constants (S, B, E, H) = (2048, 2, 1024, 16), D = 64
#define SEQ   2048
#define BATCH 2
#define NH    16
#define HD    64
#define EMB   1024

// Q is pre-scaled by log2(e)/8 at the QKV-projection epilogue, so both
// attention kernels compute exp(score/8) as exp2(S) with no per-element mul.
#define QSCALE 0.18033688011112042f

using bf16x8 = __attribute__((ext_vector_type(8))) short;  // 8 bf16 (4 VGPRs)
using f32x4  = __attribute__((ext_vector_type(4))) float;
using f32x16 = __attribute__((ext_vector_type(16))) float;

__device__ __forceinline__ unsigned short f2bf(float f) {
  unsigned int u = __float_as_uint(f);
  u += 0x7FFFu + ((u >> 16) & 1u);          // RNE
  return (unsigned short)(u >> 16);
}
__device__ __forceinline__ unsigned pk_bf16(float lo, float hi) {
  unsigned r;
  asm("v_cvt_pk_bf16_f32 %0, %1, %2" : "=v"(r) : "v"(lo), "v"(hi));
  return r;
}
// async global->LDS, 16B per lane; LDS dest = uniform base + lane*16
__device__ __forceinline__ void gload16(const void* g, void* l) {
  __builtin_amdgcn_global_load_lds(
      (const __attribute__((address_space(1))) unsigned int*)g,
      (__attribute__((address_space(3))) unsigned int*)l, 16, 0, 0);
}

// ---------------------------------------------------------------- cvt f32->bf16 (fused x, w_qkv, w_out)
__global__ __launch_bounds__(256) void cvt3_f32_bf16(
    const float* __restrict__ a, int na4,
    const float* __restrict__ b, int nb4,
    const float* __restrict__ c, int nc4,
    unsigned short* __restrict__ oa,
    unsigned short* __restrict__ ob,
    unsigned short* __restrict__ oc) {
  int i = blockIdx.x * 256 + threadIdx.x;
  const float* src;
  unsigned short* dst;
  int j = i;
  if (j < na4) { src = a; dst = oa; }
  else if ((j -= na4) < nb4) { src = b; dst = ob; }
  else { j -= nb4; if (j >= nc4) return; src = c; dst = oc; }
  float4 v = reinterpret_cast<const float4*>(src)[j];
  ushort4 o;
  o.x = f2bf(v.x); o.y = f2bf(v.y); o.z = f2bf(v.z); o.w = f2bf(v.w);
  reinterpret_cast<ushort4*>(dst)[j] = o;
}

// ---------------------------------------------------------------- GEMM C = A * B^T (+bias)
// A[M][K] bf16, B[N][K] bf16, fp32 accumulate. 128x128 tile, BK=64, 4 waves (2x2).
// Staging via global_load_lds dwordx4: linear LDS dest, pre-swizzled global src
// (slot [r][cc] holds global chunk cc^(r&7); readers use [r][j^(r&7)]).
// EPI==0: C fp32 row-major [M][N]
// EPI==1: scatter QKV -> Q (x QSCALE) / K bf16 [B][H][S][D], V -> V^T bf16 [B][H][D][S]
template <int EPI>
__global__ __launch_bounds__(256) void gemm_bt(
    const unsigned short* __restrict__ A,
    const unsigned short* __restrict__ B,
    const float* __restrict__ bias,
    float* __restrict__ Cf,
    unsigned short* __restrict__ Qb,
    unsigned short* __restrict__ Kb,
    unsigned short* __restrict__ VTb,
    int M, int N, int K) {
  __shared__ int4 As[128][8];
  __shared__ int4 Bs[128][8];
  const int tid = threadIdx.x;
  const int wid = tid >> 6, lane = tid & 63;
  const int wm = wid >> 1, wn = wid & 1;
  const int lg = lane >> 4, lr = lane & 15;
  const int lr8 = lane >> 3;                 // staging row-within-8
  const int lc8 = (lane & 7) ^ lr8;          // pre-swizzled source chunk
  const int row0 = blockIdx.x * 128, col0 = blockIdx.y * 128;
  f32x4 acc[4][4] = {};
  for (int k0 = 0; k0 < K; k0 += 64) {
#pragma unroll
    for (int i = 0; i < 4; i++) {
      const int rb = wid * 32 + i * 8;
      gload16(&A[(size_t)(row0 + rb + lr8) * K + k0 + lc8 * 8], &As[rb][0]);
      gload16(&B[(size_t)(col0 + rb + lr8) * K + k0 + lc8 * 8], &Bs[rb][0]);
    }
    __syncthreads();
#pragma unroll
    for (int ks = 0; ks < 2; ks++) {
      bf16x8 af[4], bfr[4];
#pragma unroll
      for (int mi = 0; mi < 4; mi++) {
        int r = wm * 64 + mi * 16 + lr;
        af[mi] = *reinterpret_cast<const bf16x8*>(&As[r][(ks * 4 + lg) ^ (r & 7)]);
      }
#pragma unroll
      for (int ni = 0; ni < 4; ni++) {
        int r = wn * 64 + ni * 16 + lr;
        bfr[ni] = *reinterpret_cast<const bf16x8*>(&Bs[r][(ks * 4 + lg) ^ (r & 7)]);
      }
#pragma unroll
      for (int mi = 0; mi < 4; mi++)
#pragma unroll
        for (int ni = 0; ni < 4; ni++)
          acc[mi][ni] = __builtin_amdgcn_mfma_f32_16x16x32_bf16(af[mi], bfr[ni], acc[mi][ni], 0, 0, 0);
    }
    __syncthreads();
  }
  // epilogue: C/D layout col=lane&15, row=(lane>>4)*4+r  [m89-verified]
#pragma unroll
  for (int mi = 0; mi < 4; mi++)
#pragma unroll
    for (int ni = 0; ni < 4; ni++) {
      const int row_b = row0 + wm * 64 + mi * 16 + lg * 4;   // even
      const int col = col0 + wn * 64 + ni * 16 + lr;
      const float bs = bias[col];
      float v0 = acc[mi][ni][0] + bs;
      float v1 = acc[mi][ni][1] + bs;
      float v2 = acc[mi][ni][2] + bs;
      float v3 = acc[mi][ni][3] + bs;
      if (EPI == 0) {
        Cf[(size_t)(row_b + 0) * N + col] = v0;
        Cf[(size_t)(row_b + 1) * N + col] = v1;
        Cf[(size_t)(row_b + 2) * N + col] = v2;
        Cf[(size_t)(row_b + 3) * N + col] = v3;
      } else {
        const int which = col >> 10, rr = col & 1023;
        const int hh = rr >> 6, d = rr & 63;
        if (which == 2) {
          // V^T [b][h][d][s]; rows row_b+r = s*2+b -> b=r&1, s=s0+(r>>1)
          const int s0 = row_b >> 1;
          ushort2 p0; p0.x = f2bf(v0); p0.y = f2bf(v2);   // b=0: s0, s0+1
          ushort2 p1; p1.x = f2bf(v1); p1.y = f2bf(v3);   // b=1
          *reinterpret_cast<ushort2*>(&VTb[((size_t)((0 * NH + hh) * HD + d)) * SEQ + s0]) = p0;
          *reinterpret_cast<ushort2*>(&VTb[((size_t)((1 * NH + hh) * HD + d)) * SEQ + s0]) = p1;
        } else {
          unsigned short* dst = which == 0 ? Qb : Kb;
          const float sc = (which == 0) ? QSCALE : 1.0f;
          float vv[4] = {v0 * sc, v1 * sc, v2 * sc, v3 * sc};
#pragma unroll
          for (int r = 0; r < 4; r++) {
            int s = (row_b + r) >> 1, bb = r & 1;
            dst[(size_t)((bb * NH + hh) * SEQ + s) * HD + d] = f2bf(vv[r]);
          }
        }
      }
    }
}

// ---------------------------------------------------------------- attention pass 1 (v7)
// 2-deep software pipeline: per iter, PV(t-1) [register-only MFMAs] issues
// back-to-back with QK(t), then exp/pack(t) runs on the VALU while the matrix
// pipe drains. PV operands (paq = packed P, vfr = V^T frags) carried in regs.
// K+V^T staged via global_load_lds (pre-swizzled src), double-buffered,
// 1 barrier/iter. Swapped-QK^T 32x32 (S^T = K*Q); permlane32_swap pack.
__global__ __launch_bounds__(256, 2) void attn1(
    const unsigned short* __restrict__ Qb,
    const unsigned short* __restrict__ Kb,
    const unsigned short* __restrict__ VTb,
    unsigned short* __restrict__ attn_bf,
    float* __restrict__ lbuf) {
  __shared__ int4 Kt[2][64][8];   // [t-row][chunk]; slot cc holds chunk cc^(r&7)
  __shared__ int4 Vt[2][64][8];   // [d-row][t chunks]
  const int tid = threadIdx.x;
  const int wid = tid >> 6, lane = tid & 63;
  const int l31 = lane & 31, lhi = lane >> 5;
  const int lr8 = lane >> 3;
  const int lc8 = (lane & 7) ^ lr8;
  // XCD-aware remap: XCD x gets bh groups [4x, 4x+4) -> each K/V panel on one XCD.
  const int L = blockIdx.x;
  const int v = (L & 7) * 64 + (L >> 3);
  const int bh = v >> 4, stile = v & 15;
  const int b = bh >> 4, h = bh & 15;
  const int s0 = stile * 128 + wid * 32;
  const unsigned short* Qg = Qb + (size_t)bh * SEQ * HD;
  const unsigned short* Kg = Kb + (size_t)bh * SEQ * HD;
  const unsigned short* VTg = VTb + (size_t)bh * HD * SEQ;

  // Q fragments (B-operand): s = s0 + l31, d = ks*16 + lhi*8 + j
  bf16x8 qf[4];
#pragma unroll
  for (int ks = 0; ks < 4; ks++)
    qf[ks] = *reinterpret_cast<const bf16x8*>(Qg + (size_t)(s0 + l31) * HD + ks * 16 + lhi * 8);

  auto stage = [&](int tg, int buf) {
#pragma unroll
    for (int i = 0; i < 2; i++) {
      const int rb = wid * 16 + i * 8;
      gload16(Kg + (size_t)(tg * 64 + rb + lr8) * HD + lc8 * 8, &Kt[buf][rb][0]);
      gload16(VTg + (size_t)(rb + lr8) * SEQ + tg * 64 + lc8 * 8, &Vt[buf][rb][0]);
    }
  };

  const f32x16 fz = {};   // hoisted zero accumulator
  f32x16 o[2] = {};       // [dt]: O rows s, col d = dt*32 + l31
  float ls = 0.f;
  bf16x8 paq[4];          // packed P A-fragments of previous tile
  bf16x8 vfr[2][4];       // V^T B-fragments of previous tile

  // QK helper: S^T = K * Q from Kt[cur]; lane owns s-column l31
  auto qk = [&](int cur, f32x16 st[2]) {
#pragma unroll
    for (int ti = 0; ti < 2; ti++) {
      const int row = ti * 32 + l31;
      bf16x8 kf = *reinterpret_cast<const bf16x8*>(&Kt[cur][row][(lhi) ^ (row & 7)]);
      st[ti] = __builtin_amdgcn_mfma_f32_32x32x16_bf16(kf, qf[0], fz, 0, 0, 0);
    }
#pragma unroll
    for (int ks = 1; ks < 4; ks++)
#pragma unroll
      for (int ti = 0; ti < 2; ti++) {
        const int row = ti * 32 + l31;
        bf16x8 kf = *reinterpret_cast<const bf16x8*>(&Kt[cur][row][(ks * 2 + lhi) ^ (row & 7)]);
        st[ti] = __builtin_amdgcn_mfma_f32_32x32x16_bf16(kf, qf[ks], st[ti], 0, 0, 0);
      }
  };
  // exp + in-register pack -> paq; row-sum into ls
  auto softpack = [&](const f32x16 st[2]) {
    float p[32];
    float psum = 0.f;
#pragma unroll
    for (int ti = 0; ti < 2; ti++)
#pragma unroll
      for (int r = 0; r < 16; r++) {
        float e = __builtin_amdgcn_exp2f(st[ti][r]);
        p[ti * 16 + r] = e;
        psum += e;
      }
    ls += psum;
#pragma unroll
    for (int c = 0; c < 4; c++) {
      const int ti = c >> 1, cc = c & 1;
      const int pb = ti * 16 + cc * 8;
      unsigned w0 = pk_bf16(p[pb + 0], p[pb + 1]);
      unsigned w1 = pk_bf16(p[pb + 2], p[pb + 3]);
      unsigned w2 = pk_bf16(p[pb + 4], p[pb + 5]);
      unsigned w3 = pk_bf16(p[pb + 6], p[pb + 7]);
      // one swap fills two A-frag words (lhi ? {x2,w2} : {w0,x0})
      asm volatile("v_permlane32_swap_b32 %0, %1" : "+v"(w0), "+v"(w2));
      asm volatile("v_permlane32_swap_b32 %0, %1" : "+v"(w1), "+v"(w3));
      union { unsigned u[4]; bf16x8 v; } pa;
      pa.u[0] = w0; pa.u[1] = w1; pa.u[2] = w2; pa.u[3] = w3;
      paq[c] = pa.v;
    }
  };
  auto loadv = [&](int cur) {
#pragma unroll
    for (int dt = 0; dt < 2; dt++)
#pragma unroll
      for (int c = 0; c < 4; c++) {
        const int row = dt * 32 + l31;
        vfr[dt][c] = *reinterpret_cast<const bf16x8*>(&Vt[cur][row][(c * 2 + lhi) ^ (row & 7)]);
      }
  };

  stage(0, 0);
  __syncthreads();

  // ---- prologue t = 0: no PV yet
  {
    stage(1, 1);
    f32x16 st[2];
    __builtin_amdgcn_s_setprio(1);
    qk(0, st);
    __builtin_amdgcn_s_setprio(0);
    softpack(st);
    loadv(0);
    __syncthreads();
  }

  for (int t = 1; t < 32; t++) {
    const int cur = t & 1;
    if (t + 1 < 32) stage(t + 1, cur ^ 1);
    // MFMA burst: PV(t-1) [reg-only] + QK(t); back-to-back into the matrix pipe
    f32x16 st[2];
    __builtin_amdgcn_s_setprio(1);
#pragma unroll
    for (int c = 0; c < 4; c++)
#pragma unroll
      for (int dt = 0; dt < 2; dt++)
        o[dt] = __builtin_amdgcn_mfma_f32_32x32x16_bf16(paq[c], vfr[dt][c], o[dt], 0, 0, 0);
    qk(cur, st);
    __builtin_amdgcn_s_setprio(0);
    // VALU phase overlaps matrix drain
    softpack(st);
    loadv(cur);
    __syncthreads();
  }
  // ---- epilogue: PV(31)
#pragma unroll
  for (int c = 0; c < 4; c++)
#pragma unroll
    for (int dt = 0; dt < 2; dt++)
      o[dt] = __builtin_amdgcn_mfma_f32_32x32x16_bf16(paq[c], vfr[dt][c], o[dt], 0, 0, 0);

  // full row sums: lanes l and l^32 both hold sum for s-col l31
  ls += __shfl_xor(ls, 32, 64);
  if (lhi == 0)
    lbuf[(size_t)bh * SEQ + s0 + l31] = ls;

  // epilogue: O row s = s0 + (r&3)+8*(r>>2)+4*lhi, col d = dt*32+l31
#pragma unroll
  for (int r = 0; r < 16; r++) {
    const int s_off = (r & 3) + 8 * (r >> 2) + 4 * lhi;
    float denom = __shfl(ls, s_off, 64);
    float inv = __builtin_amdgcn_rcpf(denom);
    const int s = s0 + s_off;
#pragma unroll
    for (int dt = 0; dt < 2; dt++) {
      float ov = o[dt][r] * inv;
      attn_bf[((size_t)s * BATCH + b) * EMB + h * HD + dt * 32 + l31] = f2bf(ov);
    }
  }
}

// ---------------------------------------------------------------- attention pass 2 (v7)
// Barrier-free: block = (b, 64-s-tile, 64-t-tile), 2048 blocks (4/CU, 16 waves/CU).
// No LDS staging at all — Q and K fragments read DIRECTLY from global (L1/L2
// served; the 4 waves of a block share the same K tile -> L1 hits). Only a
// read-only lls table in LDS (one barrier after init). Waves free-run; TLP
// hides all load latency. 16 h-iterations; avg in regs; coalesced final write.
__global__ __launch_bounds__(256, 4) void attn2(
    const unsigned short* __restrict__ Qb,
    const unsigned short* __restrict__ Kb,
    const float* __restrict__ lbuf,
    float* __restrict__ avg_out) {
  const int b = blockIdx.z;
  const int s0 = blockIdx.y * 64;
  const int tc0 = blockIdx.x * 64;
  __shared__ float lls[NH][64];     // 1/(NH*l)
  const int tid = threadIdx.x;
  const int wid = tid >> 6, lane = tid & 63;
  const int wm = wid >> 1, wn = wid & 1;
  const int lg = lane >> 4, lr = lane & 15;
  const size_t bh0 = (size_t)(b * NH) * SEQ;

  for (int i = tid; i < NH * 64; i += 256) {
    int hh = i >> 6, r = i & 63;
    lls[hh][r] = 1.0f / ((float)NH * lbuf[(b * NH + hh) * SEQ + s0 + r]);
  }
  __syncthreads();   // lls ready; no further barriers

  const f32x4 fz4 = {};
  f32x4 avg[2][2] = {};

  // per-lane element offsets (advance by SEQ*HD per h)
  const unsigned short* Qp[2];
  const unsigned short* Kp[2];
#pragma unroll
  for (int mi = 0; mi < 2; mi++)
    Qp[mi] = Qb + (bh0 + s0 + wm * 32 + mi * 16 + lr) * HD + lg * 8;
#pragma unroll
  for (int ni = 0; ni < 2; ni++)
    Kp[ni] = Kb + (bh0 + tc0 + wn * 32 + ni * 16 + lr) * HD + lg * 8;

#pragma unroll 2
  for (int h = 0; h < NH; h++) {
    const size_t ho = (size_t)h * SEQ * HD;
    f32x4 sacc[2][2];
#pragma unroll
    for (int ks = 0; ks < 2; ks++) {
      bf16x8 af[2], bk[2];
#pragma unroll
      for (int mi = 0; mi < 2; mi++)
        af[mi] = *reinterpret_cast<const bf16x8*>(Qp[mi] + ho + ks * 32);
#pragma unroll
      for (int ni = 0; ni < 2; ni++)
        bk[ni] = *reinterpret_cast<const bf16x8*>(Kp[ni] + ho + ks * 32);
#pragma unroll
      for (int mi = 0; mi < 2; mi++)
#pragma unroll
        for (int ni = 0; ni < 2; ni++)
          sacc[mi][ni] = __builtin_amdgcn_mfma_f32_16x16x32_bf16(
              af[mi], bk[ni], ks == 0 ? fz4 : sacc[mi][ni], 0, 0, 0);
    }
    float linv[2][4];
#pragma unroll
    for (int mi = 0; mi < 2; mi++)
#pragma unroll
      for (int r = 0; r < 4; r++)
        linv[mi][r] = lls[h][wm * 32 + mi * 16 + lg * 4 + r];
#pragma unroll
    for (int mi = 0; mi < 2; mi++)
#pragma unroll
      for (int ni = 0; ni < 2; ni++)
#pragma unroll
        for (int r = 0; r < 4; r++)
          avg[mi][ni][r] += __builtin_amdgcn_exp2f(sacc[mi][ni][r]) * linv[mi][r];
  }

  // coalesced write: 16 consecutive t per 16-lane group
#pragma unroll
  for (int mi = 0; mi < 2; mi++)
#pragma unroll
    for (int ni = 0; ni < 2; ni++)
#pragma unroll
      for (int r = 0; r < 4; r++) {
        int s = s0 + wm * 32 + mi * 16 + lg * 4 + r;
        int t = tc0 + wn * 32 + ni * 16 + lr;
        avg_out[((size_t)b * SEQ + s) * SEQ + t] = avg[mi][ni][r];
      }
}

// ---------------------------------------------------------------- launch
extern "C" void kernel_launch(void* const* d_in, const int* in_sizes, int n_in,
                              void* d_out, int out_size, void* d_ws, size_t ws_size,
                              hipStream_t stream) {
  const float* x     = (const float*)d_in[0];   // [S,B,E]
  const float* w_qkv = (const float*)d_in[1];   // [3E,E]
  const float* b_qkv = (const float*)d_in[2];   // [3E]
  const float* w_out = (const float*)d_in[3];   // [E,E]
  const float* b_out = (const float*)d_in[4];   // [E]
  float* out = (float*)d_out;                         // [S,B,E] fp32
  float* avg = out + (size_t)SEQ * BATCH * EMB;       // [B,S,S] fp32

  char* ws = (char*)d_ws;
  size_t off = 0;
  unsigned short* x_bf    = (unsigned short*)(ws + off); off += (size_t)SEQ * BATCH * EMB * 2;       // 8 MB
  unsigned short* wqkv_bf = (unsigned short*)(ws + off); off += (size_t)3 * EMB * EMB * 2;           // 6 MB
  unsigned short* wout_bf = (unsigned short*)(ws + off); off += (size_t)EMB * EMB * 2;               // 2 MB
  unsigned short* Qbuf    = (unsigned short*)(ws + off); off += (size_t)BATCH * NH * SEQ * HD * 2;   // 8 MB
  unsigned short* Kbuf    = (unsigned short*)(ws + off); off += (size_t)BATCH * NH * SEQ * HD * 2;   // 8 MB
  unsigned short* VTbuf   = (unsigned short*)(ws + off); off += (size_t)BATCH * NH * HD * SEQ * 2;   // 8 MB
  unsigned short* attn_bf = (unsigned short*)(ws + off); off += (size_t)SEQ * BATCH * EMB * 2;       // 8 MB
  float*          lbuf    = (float*)(ws + off);          off += (size_t)BATCH * NH * SEQ * 4;        // 256 KB

  // 1) convert inputs to bf16 (single fused kernel)
  {
    const int na4 = SEQ * BATCH * EMB / 4;
    const int nb4 = 3 * EMB * EMB / 4;
    const int nc4 = EMB * EMB / 4;
    const int nblk = (na4 + nb4 + nc4 + 255) / 256;
    cvt3_f32_bf16<<<nblk, 256, 0, stream>>>(x, na4, w_qkv, nb4, w_out, nc4,
                                            x_bf, wqkv_bf, wout_bf);
  }

  // 2) QKV projection, scatter to Q (pre-scaled) / K [B][H][S][D] + V^T [B][H][D][S]
  gemm_bt<1><<<dim3(SEQ * BATCH / 128, 3 * EMB / 128), 256, 0, stream>>>(
      x_bf, wqkv_bf, b_qkv, nullptr, Qbuf, Kbuf, VTbuf, SEQ * BATCH, 3 * EMB, EMB);

  // 3) attention core (v7: 2-deep PV/QK pipeline)
  attn1<<<512, 256, 0, stream>>>(Qbuf, Kbuf, VTbuf, attn_bf, lbuf);

  // 4) attention average over heads (v7: barrier-free, direct-global operands)
  attn2<<<dim3(SEQ / 64, SEQ / 64, BATCH), 256, 0, stream>>>(Qbuf, Kbuf, lbuf, avg);

  // 5) output projection -> d_out
  gemm_bt<0><<<dim3(SEQ * BATCH / 128, EMB / 128), 256, 0, stream>>>(
      attn_bf, wout_bf, b_out, out, nullptr, nullptr, nullptr, SEQ * BATCH, EMB, EMB);
}

// Round 10
// 153.450 us; speedup vs baseline: 1.5663x; 1.5663x over previous
//
#include <hip/hip_runtime.h>

// Problem constants (S, B, E, H) = (2048, 2, 1024, 16), D = 64
#define SEQ   2048
#define BATCH 2
#define NH    16
#define HD    64
#define EMB   1024

// Q is pre-scaled by log2(e)/8 at the QKV-projection epilogue, so both
// attention kernels compute exp(score/8) as exp2(S) with no per-element mul.
#define QSCALE 0.18033688011112042f

using bf16x8 = __attribute__((ext_vector_type(8))) short;  // 8 bf16 (4 VGPRs)
using f32x4  = __attribute__((ext_vector_type(4))) float;
using f32x16 = __attribute__((ext_vector_type(16))) float;

__device__ __forceinline__ unsigned short f2bf(float f) {
  unsigned int u = __float_as_uint(f);
  u += 0x7FFFu + ((u >> 16) & 1u);          // RNE
  return (unsigned short)(u >> 16);
}
__device__ __forceinline__ unsigned pk_bf16(float lo, float hi) {
  unsigned r;
  asm("v_cvt_pk_bf16_f32 %0, %1, %2" : "=v"(r) : "v"(lo), "v"(hi));
  return r;
}
// async global->LDS, 16B per lane; LDS dest = uniform base + lane*16
__device__ __forceinline__ void gload16(const void* g, void* l) {
  __builtin_amdgcn_global_load_lds(
      (const __attribute__((address_space(1))) unsigned int*)g,
      (__attribute__((address_space(3))) unsigned int*)l, 16, 0, 0);
}

// ---------------------------------------------------------------- cvt f32->bf16 (fused x, w_qkv, w_out)
__global__ __launch_bounds__(256) void cvt3_f32_bf16(
    const float* __restrict__ a, int na4,
    const float* __restrict__ b, int nb4,
    const float* __restrict__ c, int nc4,
    unsigned short* __restrict__ oa,
    unsigned short* __restrict__ ob,
    unsigned short* __restrict__ oc) {
  int i = blockIdx.x * 256 + threadIdx.x;
  const float* src;
  unsigned short* dst;
  int j = i;
  if (j < na4) { src = a; dst = oa; }
  else if ((j -= na4) < nb4) { src = b; dst = ob; }
  else { j -= nb4; if (j >= nc4) return; src = c; dst = oc; }
  float4 v = reinterpret_cast<const float4*>(src)[j];
  ushort4 o;
  o.x = f2bf(v.x); o.y = f2bf(v.y); o.z = f2bf(v.z); o.w = f2bf(v.w);
  reinterpret_cast<ushort4*>(dst)[j] = o;
}

// ---------------------------------------------------------------- GEMM C = A * B^T (+bias)
// A[M][K] bf16, B[N][K] bf16, fp32 accumulate. 128x128 tile, BK=64, 4 waves (2x2).
// Staging via global_load_lds dwordx4: linear LDS dest, pre-swizzled global src.
// XCD-aware bijective block swizzle (nwg % 8 == 0 for all our launches).
// EPI==0: C fp32 row-major [M][N]
// EPI==1: scatter QKV -> Q (x QSCALE) / K bf16 [B][H][S][D], V -> V^T bf16 [B][H][D][S]
template <int EPI>
__global__ __launch_bounds__(256) void gemm_bt(
    const unsigned short* __restrict__ A,
    const unsigned short* __restrict__ B,
    const float* __restrict__ bias,
    float* __restrict__ Cf,
    unsigned short* __restrict__ Qb,
    unsigned short* __restrict__ Kb,
    unsigned short* __restrict__ VTb,
    int M, int N, int K) {
  __shared__ int4 As[128][8];
  __shared__ int4 Bs[128][8];
  const int tid = threadIdx.x;
  const int wid = tid >> 6, lane = tid & 63;
  const int wm = wid >> 1, wn = wid & 1;
  const int lg = lane >> 4, lr = lane & 15;
  const int lr8 = lane >> 3;                 // staging row-within-8
  const int lc8 = (lane & 7) ^ lr8;          // pre-swizzled source chunk
  // XCD-aware swizzle: XCD x (= linear id % 8) gets a contiguous chunk of tiles.
  const int nbx = gridDim.x;
  const int nwg = nbx * gridDim.y;
  const int id = blockIdx.x + nbx * blockIdx.y;
  const int swz = (id & 7) * (nwg >> 3) + (id >> 3);
  const int row0 = (swz % nbx) * 128, col0 = (swz / nbx) * 128;
  f32x4 acc[4][4] = {};
  for (int k0 = 0; k0 < K; k0 += 64) {
#pragma unroll
    for (int i = 0; i < 4; i++) {
      const int rb = wid * 32 + i * 8;
      gload16(&A[(size_t)(row0 + rb + lr8) * K + k0 + lc8 * 8], &As[rb][0]);
      gload16(&B[(size_t)(col0 + rb + lr8) * K + k0 + lc8 * 8], &Bs[rb][0]);
    }
    __syncthreads();
#pragma unroll
    for (int ks = 0; ks < 2; ks++) {
      bf16x8 af[4], bfr[4];
#pragma unroll
      for (int mi = 0; mi < 4; mi++) {
        int r = wm * 64 + mi * 16 + lr;
        af[mi] = *reinterpret_cast<const bf16x8*>(&As[r][(ks * 4 + lg) ^ (r & 7)]);
      }
#pragma unroll
      for (int ni = 0; ni < 4; ni++) {
        int r = wn * 64 + ni * 16 + lr;
        bfr[ni] = *reinterpret_cast<const bf16x8*>(&Bs[r][(ks * 4 + lg) ^ (r & 7)]);
      }
#pragma unroll
      for (int mi = 0; mi < 4; mi++)
#pragma unroll
        for (int ni = 0; ni < 4; ni++)
          acc[mi][ni] = __builtin_amdgcn_mfma_f32_16x16x32_bf16(af[mi], bfr[ni], acc[mi][ni], 0, 0, 0);
    }
    __syncthreads();
  }
  // epilogue: C/D layout col=lane&15, row=(lane>>4)*4+r  [m89-verified]
#pragma unroll
  for (int mi = 0; mi < 4; mi++)
#pragma unroll
    for (int ni = 0; ni < 4; ni++) {
      const int row_b = row0 + wm * 64 + mi * 16 + lg * 4;   // even
      const int col = col0 + wn * 64 + ni * 16 + lr;
      const float bs = bias[col];
      float v0 = acc[mi][ni][0] + bs;
      float v1 = acc[mi][ni][1] + bs;
      float v2 = acc[mi][ni][2] + bs;
      float v3 = acc[mi][ni][3] + bs;
      if (EPI == 0) {
        Cf[(size_t)(row_b + 0) * N + col] = v0;
        Cf[(size_t)(row_b + 1) * N + col] = v1;
        Cf[(size_t)(row_b + 2) * N + col] = v2;
        Cf[(size_t)(row_b + 3) * N + col] = v3;
      } else {
        const int which = col >> 10, rr = col & 1023;
        const int hh = rr >> 6, d = rr & 63;
        if (which == 2) {
          // V^T [b][h][d][s]; rows row_b+r = s*2+b -> b=r&1, s=s0+(r>>1)
          const int s0 = row_b >> 1;
          ushort2 p0; p0.x = f2bf(v0); p0.y = f2bf(v2);   // b=0: s0, s0+1
          ushort2 p1; p1.x = f2bf(v1); p1.y = f2bf(v3);   // b=1
          *reinterpret_cast<ushort2*>(&VTb[((size_t)((0 * NH + hh) * HD + d)) * SEQ + s0]) = p0;
          *reinterpret_cast<ushort2*>(&VTb[((size_t)((1 * NH + hh) * HD + d)) * SEQ + s0]) = p1;
        } else {
          unsigned short* dst = which == 0 ? Qb : Kb;
          const float sc = (which == 0) ? QSCALE : 1.0f;
          float vv[4] = {v0 * sc, v1 * sc, v2 * sc, v3 * sc};
#pragma unroll
          for (int r = 0; r < 4; r++) {
            int s = (row_b + r) >> 1, bb = r & 1;
            dst[(size_t)((bb * NH + hh) * SEQ + s) * HD + d] = f2bf(vv[r]);
          }
        }
      }
    }
}

// ---------------------------------------------------------------- attention pass 1 (v7)
// 2-deep software pipeline: per iter, PV(t-1) [register-only MFMAs] issues
// back-to-back with QK(t), then exp/pack(t) runs on the VALU while the matrix
// pipe drains. PV operands (paq = packed P, vfr = V^T frags) carried in regs.
// K+V^T staged via global_load_lds (pre-swizzled src), double-buffered,
// 1 barrier/iter. Swapped-QK^T 32x32 (S^T = K*Q); permlane32_swap pack.
__global__ __launch_bounds__(256, 2) void attn1(
    const unsigned short* __restrict__ Qb,
    const unsigned short* __restrict__ Kb,
    const unsigned short* __restrict__ VTb,
    unsigned short* __restrict__ attn_bf,
    float* __restrict__ lbuf) {
  __shared__ int4 Kt[2][64][8];   // [t-row][chunk]; slot cc holds chunk cc^(r&7)
  __shared__ int4 Vt[2][64][8];   // [d-row][t chunks]
  const int tid = threadIdx.x;
  const int wid = tid >> 6, lane = tid & 63;
  const int l31 = lane & 31, lhi = lane >> 5;
  const int lr8 = lane >> 3;
  const int lc8 = (lane & 7) ^ lr8;
  // XCD-aware remap: XCD x gets bh groups [4x, 4x+4) -> each K/V panel on one XCD.
  const int L = blockIdx.x;
  const int v = (L & 7) * 64 + (L >> 3);
  const int bh = v >> 4, stile = v & 15;
  const int b = bh >> 4, h = bh & 15;
  const int s0 = stile * 128 + wid * 32;
  const unsigned short* Qg = Qb + (size_t)bh * SEQ * HD;
  const unsigned short* Kg = Kb + (size_t)bh * SEQ * HD;
  const unsigned short* VTg = VTb + (size_t)bh * HD * SEQ;

  // Q fragments (B-operand): s = s0 + l31, d = ks*16 + lhi*8 + j
  bf16x8 qf[4];
#pragma unroll
  for (int ks = 0; ks < 4; ks++)
    qf[ks] = *reinterpret_cast<const bf16x8*>(Qg + (size_t)(s0 + l31) * HD + ks * 16 + lhi * 8);

  auto stage = [&](int tg, int buf) {
#pragma unroll
    for (int i = 0; i < 2; i++) {
      const int rb = wid * 16 + i * 8;
      gload16(Kg + (size_t)(tg * 64 + rb + lr8) * HD + lc8 * 8, &Kt[buf][rb][0]);
      gload16(VTg + (size_t)(rb + lr8) * SEQ + tg * 64 + lc8 * 8, &Vt[buf][rb][0]);
    }
  };

  const f32x16 fz = {};   // hoisted zero accumulator
  f32x16 o[2] = {};       // [dt]: O rows s, col d = dt*32 + l31
  float ls = 0.f;
  bf16x8 paq[4];          // packed P A-fragments of previous tile
  bf16x8 vfr[2][4];       // V^T B-fragments of previous tile

  // QK helper: S^T = K * Q from Kt[cur]; lane owns s-column l31
  auto qk = [&](int cur, f32x16 st[2]) {
#pragma unroll
    for (int ti = 0; ti < 2; ti++) {
      const int row = ti * 32 + l31;
      bf16x8 kf = *reinterpret_cast<const bf16x8*>(&Kt[cur][row][(lhi) ^ (row & 7)]);
      st[ti] = __builtin_amdgcn_mfma_f32_32x32x16_bf16(kf, qf[0], fz, 0, 0, 0);
    }
#pragma unroll
    for (int ks = 1; ks < 4; ks++)
#pragma unroll
      for (int ti = 0; ti < 2; ti++) {
        const int row = ti * 32 + l31;
        bf16x8 kf = *reinterpret_cast<const bf16x8*>(&Kt[cur][row][(ks * 2 + lhi) ^ (row & 7)]);
        st[ti] = __builtin_amdgcn_mfma_f32_32x32x16_bf16(kf, qf[ks], st[ti], 0, 0, 0);
      }
  };
  // exp + in-register pack -> paq; row-sum into ls
  auto softpack = [&](const f32x16 st[2]) {
    float p[32];
    float psum = 0.f;
#pragma unroll
    for (int ti = 0; ti < 2; ti++)
#pragma unroll
      for (int r = 0; r < 16; r++) {
        float e = __builtin_amdgcn_exp2f(st[ti][r]);
        p[ti * 16 + r] = e;
        psum += e;
      }
    ls += psum;
#pragma unroll
    for (int c = 0; c < 4; c++) {
      const int ti = c >> 1, cc = c & 1;
      const int pb = ti * 16 + cc * 8;
      unsigned w0 = pk_bf16(p[pb + 0], p[pb + 1]);
      unsigned w1 = pk_bf16(p[pb + 2], p[pb + 3]);
      unsigned w2 = pk_bf16(p[pb + 4], p[pb + 5]);
      unsigned w3 = pk_bf16(p[pb + 6], p[pb + 7]);
      // one swap fills two A-frag words (lhi ? {x2,w2} : {w0,x0})
      asm volatile("v_permlane32_swap_b32 %0, %1" : "+v"(w0), "+v"(w2));
      asm volatile("v_permlane32_swap_b32 %0, %1" : "+v"(w1), "+v"(w3));
      union { unsigned u[4]; bf16x8 v; } pa;
      pa.u[0] = w0; pa.u[1] = w1; pa.u[2] = w2; pa.u[3] = w3;
      paq[c] = pa.v;
    }
  };
  auto loadv = [&](int cur) {
#pragma unroll
    for (int dt = 0; dt < 2; dt++)
#pragma unroll
      for (int c = 0; c < 4; c++) {
        const int row = dt * 32 + l31;
        vfr[dt][c] = *reinterpret_cast<const bf16x8*>(&Vt[cur][row][(c * 2 + lhi) ^ (row & 7)]);
      }
  };

  stage(0, 0);
  __syncthreads();

  // ---- prologue t = 0: no PV yet
  {
    stage(1, 1);
    f32x16 st[2];
    __builtin_amdgcn_s_setprio(1);
    qk(0, st);
    __builtin_amdgcn_s_setprio(0);
    softpack(st);
    loadv(0);
    __syncthreads();
  }

  for (int t = 1; t < 32; t++) {
    const int cur = t & 1;
    if (t + 1 < 32) stage(t + 1, cur ^ 1);
    // MFMA burst: PV(t-1) [reg-only] + QK(t); back-to-back into the matrix pipe
    f32x16 st[2];
    __builtin_amdgcn_s_setprio(1);
#pragma unroll
    for (int c = 0; c < 4; c++)
#pragma unroll
      for (int dt = 0; dt < 2; dt++)
        o[dt] = __builtin_amdgcn_mfma_f32_32x32x16_bf16(paq[c], vfr[dt][c], o[dt], 0, 0, 0);
    qk(cur, st);
    __builtin_amdgcn_s_setprio(0);
    // VALU phase overlaps matrix drain
    softpack(st);
    loadv(cur);
    __syncthreads();
  }
  // ---- epilogue: PV(31)
#pragma unroll
  for (int c = 0; c < 4; c++)
#pragma unroll
    for (int dt = 0; dt < 2; dt++)
      o[dt] = __builtin_amdgcn_mfma_f32_32x32x16_bf16(paq[c], vfr[dt][c], o[dt], 0, 0, 0);

  // full row sums: lanes l and l^32 both hold sum for s-col l31
  ls += __shfl_xor(ls, 32, 64);
  if (lhi == 0)
    lbuf[(size_t)bh * SEQ + s0 + l31] = ls;

  // epilogue: O row s = s0 + (r&3)+8*(r>>2)+4*lhi, col d = dt*32+l31
#pragma unroll
  for (int r = 0; r < 16; r++) {
    const int s_off = (r & 3) + 8 * (r >> 2) + 4 * lhi;
    float denom = __shfl(ls, s_off, 64);
    float inv = __builtin_amdgcn_rcpf(denom);
    const int s = s0 + s_off;
#pragma unroll
    for (int dt = 0; dt < 2; dt++) {
      float ov = o[dt][r] * inv;
      attn_bf[((size_t)s * BATCH + b) * EMB + h * HD + dt * 32 + l31] = f2bf(ov);
    }
  }
}

// ---------------------------------------------------------------- attention pass 2 (v5 — reverted known-good)
// Per (b, 64-row s-tile, 256-col t-chunk): h-outer recompute of scores.
// K double-buffered + Q staged via global_load_lds (pre-swizzled source),
// 1 barrier/iter, raw exp2, avg in regs, hoisted zero acc.
__global__ __launch_bounds__(256) void attn2(
    const unsigned short* __restrict__ Qb,
    const unsigned short* __restrict__ Kb,
    const float* __restrict__ lbuf,
    float* __restrict__ avg_out) {
  const int b = blockIdx.z;
  const int s0 = blockIdx.y * 64;
  const int tc0 = blockIdx.x * 256;
  __shared__ int4 Qs[64][8];        // 8 KB
  __shared__ int4 Ks[2][64][8];     // 16 KB double-buffered
  __shared__ float lls[NH][64];     // 1/(NH*l)
  const int tid = threadIdx.x;
  const int wid = tid >> 6, lane = tid & 63;
  const int wm = wid >> 1, wn = wid & 1;
  const int lg = lane >> 4, lr = lane & 15;
  const int lr8 = lane >> 3;
  const int lc8 = (lane & 7) ^ lr8;

  for (int i = tid; i < NH * 64; i += 256) {
    int hh = i >> 6, r = i & 63;
    lls[hh][r] = 1.0f / ((float)NH * lbuf[(b * NH + hh) * SEQ + s0 + r]);
  }

  const size_t bh0 = (size_t)(b * NH) * SEQ;

  auto stageK = [&](const unsigned short* src, int buf) {
#pragma unroll
    for (int i = 0; i < 2; i++) {
      const int rb = wid * 16 + i * 8;
      gload16(src + (size_t)(rb + lr8) * HD + lc8 * 8, &Ks[buf][rb][0]);
    }
  };
  auto stageQ = [&](const unsigned short* src) {
#pragma unroll
    for (int i = 0; i < 2; i++) {
      const int rb = wid * 16 + i * 8;
      gload16(src + (size_t)(rb + lr8) * HD + lc8 * 8, &Qs[rb][0]);
    }
  };

  stageQ(Qb + (bh0 + s0) * HD);
  stageK(Kb + (bh0 + tc0) * HD, 0);
  __syncthreads();

  const f32x4 fz4 = {};
  f32x4 avg[4][2][2] = {};

  for (int h = 0; h < NH; h++) {
    bf16x8 af[2][2];
#pragma unroll
    for (int mi = 0; mi < 2; mi++) {
      int r = wm * 32 + mi * 16 + lr;
#pragma unroll
      for (int ks = 0; ks < 2; ks++)
        af[mi][ks] = *reinterpret_cast<const bf16x8*>(&Qs[r][(ks * 4 + lg) ^ (r & 7)]);
    }
    float linv[2][4];
#pragma unroll
    for (int mi = 0; mi < 2; mi++)
#pragma unroll
      for (int r = 0; r < 4; r++)
        linv[mi][r] = lls[h][wm * 32 + mi * 16 + lg * 4 + r];

    const unsigned short* Kgh = Kb + (bh0 + (size_t)h * SEQ + tc0) * HD;

    for (int t0 = 0; t0 < 4; t0++) {
      const int cur = t0 & 1;
      if (t0 < 3) {
        stageK(Kgh + (size_t)(t0 + 1) * 64 * HD, cur ^ 1);
      } else if (h + 1 < NH) {
        stageK(Kb + (bh0 + (size_t)(h + 1) * SEQ + tc0) * HD, cur ^ 1);
        stageQ(Qb + (bh0 + (size_t)(h + 1) * SEQ + s0) * HD);
      }
      f32x4 sacc[2][2];
      __builtin_amdgcn_s_setprio(1);
#pragma unroll
      for (int ks = 0; ks < 2; ks++) {
        bf16x8 bk[2];
#pragma unroll
        for (int ni = 0; ni < 2; ni++) {
          int rk = wn * 32 + ni * 16 + lr;
          bk[ni] = *reinterpret_cast<const bf16x8*>(&Ks[cur][rk][(ks * 4 + lg) ^ (rk & 7)]);
        }
#pragma unroll
        for (int mi = 0; mi < 2; mi++)
#pragma unroll
          for (int ni = 0; ni < 2; ni++)
            sacc[mi][ni] = __builtin_amdgcn_mfma_f32_16x16x32_bf16(
                af[mi][ks], bk[ni], ks == 0 ? fz4 : sacc[mi][ni], 0, 0, 0);
      }
      __builtin_amdgcn_s_setprio(0);
#pragma unroll
      for (int mi = 0; mi < 2; mi++)
#pragma unroll
        for (int ni = 0; ni < 2; ni++)
#pragma unroll
          for (int r = 0; r < 4; r++)
            avg[t0][mi][ni][r] += __builtin_amdgcn_exp2f(sacc[mi][ni][r]) * linv[mi][r];
      __syncthreads();
    }
  }

#pragma unroll
  for (int t0 = 0; t0 < 4; t0++)
#pragma unroll
    for (int mi = 0; mi < 2; mi++)
#pragma unroll
      for (int ni = 0; ni < 2; ni++)
#pragma unroll
        for (int r = 0; r < 4; r++) {
          int s = s0 + wm * 32 + mi * 16 + lg * 4 + r;
          int t = tc0 + t0 * 64 + wn * 32 + ni * 16 + lr;
          avg_out[((size_t)b * SEQ + s) * SEQ + t] = avg[t0][mi][ni][r];
        }
}

// ---------------------------------------------------------------- launch
extern "C" void kernel_launch(void* const* d_in, const int* in_sizes, int n_in,
                              void* d_out, int out_size, void* d_ws, size_t ws_size,
                              hipStream_t stream) {
  const float* x     = (const float*)d_in[0];   // [S,B,E]
  const float* w_qkv = (const float*)d_in[1];   // [3E,E]
  const float* b_qkv = (const float*)d_in[2];   // [3E]
  const float* w_out = (const float*)d_in[3];   // [E,E]
  const float* b_out = (const float*)d_in[4];   // [E]
  float* out = (float*)d_out;                         // [S,B,E] fp32
  float* avg = out + (size_t)SEQ * BATCH * EMB;       // [B,S,S] fp32

  char* ws = (char*)d_ws;
  size_t off = 0;
  unsigned short* x_bf    = (unsigned short*)(ws + off); off += (size_t)SEQ * BATCH * EMB * 2;       // 8 MB
  unsigned short* wqkv_bf = (unsigned short*)(ws + off); off += (size_t)3 * EMB * EMB * 2;           // 6 MB
  unsigned short* wout_bf = (unsigned short*)(ws + off); off += (size_t)EMB * EMB * 2;               // 2 MB
  unsigned short* Qbuf    = (unsigned short*)(ws + off); off += (size_t)BATCH * NH * SEQ * HD * 2;   // 8 MB
  unsigned short* Kbuf    = (unsigned short*)(ws + off); off += (size_t)BATCH * NH * SEQ * HD * 2;   // 8 MB
  unsigned short* VTbuf   = (unsigned short*)(ws + off); off += (size_t)BATCH * NH * HD * SEQ * 2;   // 8 MB
  unsigned short* attn_bf = (unsigned short*)(ws + off); off += (size_t)SEQ * BATCH * EMB * 2;       // 8 MB
  float*          lbuf    = (float*)(ws + off);          off += (size_t)BATCH * NH * SEQ * 4;        // 256 KB

  // 1) convert inputs to bf16 (single fused kernel)
  {
    const int na4 = SEQ * BATCH * EMB / 4;
    const int nb4 = 3 * EMB * EMB / 4;
    const int nc4 = EMB * EMB / 4;
    const int nblk = (na4 + nb4 + nc4 + 255) / 256;
    cvt3_f32_bf16<<<nblk, 256, 0, stream>>>(x, na4, w_qkv, nb4, w_out, nc4,
                                            x_bf, wqkv_bf, wout_bf);
  }

  // 2) QKV projection, scatter to Q (pre-scaled) / K [B][H][S][D] + V^T [B][H][D][S]
  gemm_bt<1><<<dim3(SEQ * BATCH / 128, 3 * EMB / 128), 256, 0, stream>>>(
      x_bf, wqkv_bf, b_qkv, nullptr, Qbuf, Kbuf, VTbuf, SEQ * BATCH, 3 * EMB, EMB);

  // 3) attention core (v7: 2-deep PV/QK pipeline)
  attn1<<<512, 256, 0, stream>>>(Qbuf, Kbuf, VTbuf, attn_bf, lbuf);

  // 4) attention average over heads (v5: reverted known-good structure)
  attn2<<<dim3(SEQ / 256, SEQ / 64, BATCH), 256, 0, stream>>>(Qbuf, Kbuf, lbuf, avg);

  // 5) output projection -> d_out
  gemm_bt<0><<<dim3(SEQ * BATCH / 128, EMB / 128), 256, 0, stream>>>(
      attn_bf, wout_bf, b_out, out, nullptr, nullptr, nullptr, SEQ * BATCH, EMB, EMB);
}

// Round 11
// 145.060 us; speedup vs baseline: 1.6569x; 1.0578x over previous
//
#include <hip/hip_runtime.h>

// Problem constants (S, B, E, H) = (2048, 2, 1024, 16), D = 64
#define SEQ   2048
#define BATCH 2
#define NH    16
#define HD    64
#define EMB   1024

// Q is pre-scaled by log2(e)/8 at the QKV-projection epilogue, so both
// attention kernels compute exp(score/8) as exp2(S) with no per-element mul.
#define QSCALE 0.18033688011112042f

using bf16x8 = __attribute__((ext_vector_type(8))) short;  // 8 bf16 (4 VGPRs)
using f32x4  = __attribute__((ext_vector_type(4))) float;
using f32x16 = __attribute__((ext_vector_type(16))) float;

__device__ __forceinline__ unsigned short f2bf(float f) {
  unsigned int u = __float_as_uint(f);
  u += 0x7FFFu + ((u >> 16) & 1u);          // RNE
  return (unsigned short)(u >> 16);
}
__device__ __forceinline__ unsigned pk_bf16(float lo, float hi) {
  unsigned r;
  asm("v_cvt_pk_bf16_f32 %0, %1, %2" : "=v"(r) : "v"(lo), "v"(hi));
  return r;
}
// async global->LDS, 16B per lane; LDS dest = uniform base + lane*16
__device__ __forceinline__ void gload16(const void* g, void* l) {
  __builtin_amdgcn_global_load_lds(
      (const __attribute__((address_space(1))) unsigned int*)g,
      (__attribute__((address_space(3))) unsigned int*)l, 16, 0, 0);
}

// ---------------------------------------------------------------- cvt f32->bf16 (fused x, w_qkv, w_out)
__global__ __launch_bounds__(256) void cvt3_f32_bf16(
    const float* __restrict__ a, int na4,
    const float* __restrict__ b, int nb4,
    const float* __restrict__ c, int nc4,
    unsigned short* __restrict__ oa,
    unsigned short* __restrict__ ob,
    unsigned short* __restrict__ oc) {
  int i = blockIdx.x * 256 + threadIdx.x;
  const float* src;
  unsigned short* dst;
  int j = i;
  if (j < na4) { src = a; dst = oa; }
  else if ((j -= na4) < nb4) { src = b; dst = ob; }
  else { j -= nb4; if (j >= nc4) return; src = c; dst = oc; }
  float4 v = reinterpret_cast<const float4*>(src)[j];
  ushort4 o;
  o.x = f2bf(v.x); o.y = f2bf(v.y); o.z = f2bf(v.z); o.w = f2bf(v.w);
  reinterpret_cast<ushort4*>(dst)[j] = o;
}

// ---------------------------------------------------------------- GEMM C = A * B^T (+bias)
// A[M][K] bf16, B[N][K] bf16, fp32 accumulate. 128x128 tile, BK=64, 4 waves (2x2).
// Staging via global_load_lds dwordx4: linear LDS dest, pre-swizzled global src
// (slot [r][cc] holds global chunk cc^(r&7); readers use [r][j^(r&7)]).
// EPI==0: C fp32 row-major [M][N]
// EPI==1: scatter QKV -> Q (x QSCALE) / K bf16 [B][H][S][D], V -> V^T bf16 [B][H][D][S]
template <int EPI>
__global__ __launch_bounds__(256) void gemm_bt(
    const unsigned short* __restrict__ A,
    const unsigned short* __restrict__ B,
    const float* __restrict__ bias,
    float* __restrict__ Cf,
    unsigned short* __restrict__ Qb,
    unsigned short* __restrict__ Kb,
    unsigned short* __restrict__ VTb,
    int M, int N, int K) {
  __shared__ int4 As[128][8];
  __shared__ int4 Bs[128][8];
  const int tid = threadIdx.x;
  const int wid = tid >> 6, lane = tid & 63;
  const int wm = wid >> 1, wn = wid & 1;
  const int lg = lane >> 4, lr = lane & 15;
  const int lr8 = lane >> 3;                 // staging row-within-8
  const int lc8 = (lane & 7) ^ lr8;          // pre-swizzled source chunk
  const int row0 = blockIdx.x * 128, col0 = blockIdx.y * 128;
  f32x4 acc[4][4] = {};
  for (int k0 = 0; k0 < K; k0 += 64) {
#pragma unroll
    for (int i = 0; i < 4; i++) {
      const int rb = wid * 32 + i * 8;
      gload16(&A[(size_t)(row0 + rb + lr8) * K + k0 + lc8 * 8], &As[rb][0]);
      gload16(&B[(size_t)(col0 + rb + lr8) * K + k0 + lc8 * 8], &Bs[rb][0]);
    }
    __syncthreads();
#pragma unroll
    for (int ks = 0; ks < 2; ks++) {
      bf16x8 af[4], bfr[4];
#pragma unroll
      for (int mi = 0; mi < 4; mi++) {
        int r = wm * 64 + mi * 16 + lr;
        af[mi] = *reinterpret_cast<const bf16x8*>(&As[r][(ks * 4 + lg) ^ (r & 7)]);
      }
#pragma unroll
      for (int ni = 0; ni < 4; ni++) {
        int r = wn * 64 + ni * 16 + lr;
        bfr[ni] = *reinterpret_cast<const bf16x8*>(&Bs[r][(ks * 4 + lg) ^ (r & 7)]);
      }
#pragma unroll
      for (int mi = 0; mi < 4; mi++)
#pragma unroll
        for (int ni = 0; ni < 4; ni++)
          acc[mi][ni] = __builtin_amdgcn_mfma_f32_16x16x32_bf16(af[mi], bfr[ni], acc[mi][ni], 0, 0, 0);
    }
    __syncthreads();
  }
  // epilogue: C/D layout col=lane&15, row=(lane>>4)*4+r  [m89-verified]
#pragma unroll
  for (int mi = 0; mi < 4; mi++)
#pragma unroll
    for (int ni = 0; ni < 4; ni++) {
      const int row_b = row0 + wm * 64 + mi * 16 + lg * 4;   // even
      const int col = col0 + wn * 64 + ni * 16 + lr;
      const float bs = bias[col];
      float v0 = acc[mi][ni][0] + bs;
      float v1 = acc[mi][ni][1] + bs;
      float v2 = acc[mi][ni][2] + bs;
      float v3 = acc[mi][ni][3] + bs;
      if (EPI == 0) {
        Cf[(size_t)(row_b + 0) * N + col] = v0;
        Cf[(size_t)(row_b + 1) * N + col] = v1;
        Cf[(size_t)(row_b + 2) * N + col] = v2;
        Cf[(size_t)(row_b + 3) * N + col] = v3;
      } else {
        const int which = col >> 10, rr = col & 1023;
        const int hh = rr >> 6, d = rr & 63;
        if (which == 2) {
          // V^T [b][h][d][s]; rows row_b+r = s*2+b -> b=r&1, s=s0+(r>>1)
          const int s0 = row_b >> 1;
          ushort2 p0; p0.x = f2bf(v0); p0.y = f2bf(v2);   // b=0: s0, s0+1
          ushort2 p1; p1.x = f2bf(v1); p1.y = f2bf(v3);   // b=1
          *reinterpret_cast<ushort2*>(&VTb[((size_t)((0 * NH + hh) * HD + d)) * SEQ + s0]) = p0;
          *reinterpret_cast<ushort2*>(&VTb[((size_t)((1 * NH + hh) * HD + d)) * SEQ + s0]) = p1;
        } else {
          unsigned short* dst = which == 0 ? Qb : Kb;
          const float sc = (which == 0) ? QSCALE : 1.0f;
          float vv[4] = {v0 * sc, v1 * sc, v2 * sc, v3 * sc};
#pragma unroll
          for (int r = 0; r < 4; r++) {
            int s = (row_b + r) >> 1, bb = r & 1;
            dst[(size_t)((bb * NH + hh) * SEQ + s) * HD + d] = f2bf(vv[r]);
          }
        }
      }
    }
}

// ---------------------------------------------------------------- attention pass 1 (v7)
// 2-deep software pipeline: per iter, PV(t-1) [register-only MFMAs] issues
// back-to-back with QK(t), then exp/pack(t) runs on the VALU while the matrix
// pipe drains. PV operands (paq = packed P, vfr = V^T frags) carried in regs.
// K+V^T staged via global_load_lds (pre-swizzled src), double-buffered,
// 1 barrier/iter. Swapped-QK^T 32x32 (S^T = K*Q); permlane32_swap pack.
__global__ __launch_bounds__(256, 2) void attn1(
    const unsigned short* __restrict__ Qb,
    const unsigned short* __restrict__ Kb,
    const unsigned short* __restrict__ VTb,
    unsigned short* __restrict__ attn_bf,
    float* __restrict__ lbuf) {
  __shared__ int4 Kt[2][64][8];   // [t-row][chunk]; slot cc holds chunk cc^(r&7)
  __shared__ int4 Vt[2][64][8];   // [d-row][t chunks]
  const int tid = threadIdx.x;
  const int wid = tid >> 6, lane = tid & 63;
  const int l31 = lane & 31, lhi = lane >> 5;
  const int lr8 = lane >> 3;
  const int lc8 = (lane & 7) ^ lr8;
  // XCD-aware remap: XCD x gets bh groups [4x, 4x+4) -> each K/V panel on one XCD.
  const int L = blockIdx.x;
  const int v = (L & 7) * 64 + (L >> 3);
  const int bh = v >> 4, stile = v & 15;
  const int b = bh >> 4, h = bh & 15;
  const int s0 = stile * 128 + wid * 32;
  const unsigned short* Qg = Qb + (size_t)bh * SEQ * HD;
  const unsigned short* Kg = Kb + (size_t)bh * SEQ * HD;
  const unsigned short* VTg = VTb + (size_t)bh * HD * SEQ;

  // Q fragments (B-operand): s = s0 + l31, d = ks*16 + lhi*8 + j
  bf16x8 qf[4];
#pragma unroll
  for (int ks = 0; ks < 4; ks++)
    qf[ks] = *reinterpret_cast<const bf16x8*>(Qg + (size_t)(s0 + l31) * HD + ks * 16 + lhi * 8);

  auto stage = [&](int tg, int buf) {
#pragma unroll
    for (int i = 0; i < 2; i++) {
      const int rb = wid * 16 + i * 8;
      gload16(Kg + (size_t)(tg * 64 + rb + lr8) * HD + lc8 * 8, &Kt[buf][rb][0]);
      gload16(VTg + (size_t)(rb + lr8) * SEQ + tg * 64 + lc8 * 8, &Vt[buf][rb][0]);
    }
  };

  const f32x16 fz = {};   // hoisted zero accumulator
  f32x16 o[2] = {};       // [dt]: O rows s, col d = dt*32 + l31
  float ls = 0.f;
  bf16x8 paq[4];          // packed P A-fragments of previous tile
  bf16x8 vfr[2][4];       // V^T B-fragments of previous tile

  // QK helper: S^T = K * Q from Kt[cur]; lane owns s-column l31
  auto qk = [&](int cur, f32x16 st[2]) {
#pragma unroll
    for (int ti = 0; ti < 2; ti++) {
      const int row = ti * 32 + l31;
      bf16x8 kf = *reinterpret_cast<const bf16x8*>(&Kt[cur][row][(lhi) ^ (row & 7)]);
      st[ti] = __builtin_amdgcn_mfma_f32_32x32x16_bf16(kf, qf[0], fz, 0, 0, 0);
    }
#pragma unroll
    for (int ks = 1; ks < 4; ks++)
#pragma unroll
      for (int ti = 0; ti < 2; ti++) {
        const int row = ti * 32 + l31;
        bf16x8 kf = *reinterpret_cast<const bf16x8*>(&Kt[cur][row][(ks * 2 + lhi) ^ (row & 7)]);
        st[ti] = __builtin_amdgcn_mfma_f32_32x32x16_bf16(kf, qf[ks], st[ti], 0, 0, 0);
      }
  };
  // exp + in-register pack -> paq; row-sum into ls
  auto softpack = [&](const f32x16 st[2]) {
    float p[32];
    float psum = 0.f;
#pragma unroll
    for (int ti = 0; ti < 2; ti++)
#pragma unroll
      for (int r = 0; r < 16; r++) {
        float e = __builtin_amdgcn_exp2f(st[ti][r]);
        p[ti * 16 + r] = e;
        psum += e;
      }
    ls += psum;
#pragma unroll
    for (int c = 0; c < 4; c++) {
      const int ti = c >> 1, cc = c & 1;
      const int pb = ti * 16 + cc * 8;
      unsigned w0 = pk_bf16(p[pb + 0], p[pb + 1]);
      unsigned w1 = pk_bf16(p[pb + 2], p[pb + 3]);
      unsigned w2 = pk_bf16(p[pb + 4], p[pb + 5]);
      unsigned w3 = pk_bf16(p[pb + 6], p[pb + 7]);
      // one swap fills two A-frag words (lhi ? {x2,w2} : {w0,x0})
      asm volatile("v_permlane32_swap_b32 %0, %1" : "+v"(w0), "+v"(w2));
      asm volatile("v_permlane32_swap_b32 %0, %1" : "+v"(w1), "+v"(w3));
      union { unsigned u[4]; bf16x8 v; } pa;
      pa.u[0] = w0; pa.u[1] = w1; pa.u[2] = w2; pa.u[3] = w3;
      paq[c] = pa.v;
    }
  };
  auto loadv = [&](int cur) {
#pragma unroll
    for (int dt = 0; dt < 2; dt++)
#pragma unroll
      for (int c = 0; c < 4; c++) {
        const int row = dt * 32 + l31;
        vfr[dt][c] = *reinterpret_cast<const bf16x8*>(&Vt[cur][row][(c * 2 + lhi) ^ (row & 7)]);
      }
  };

  stage(0, 0);
  __syncthreads();

  // ---- prologue t = 0: no PV yet
  {
    stage(1, 1);
    f32x16 st[2];
    __builtin_amdgcn_s_setprio(1);
    qk(0, st);
    __builtin_amdgcn_s_setprio(0);
    softpack(st);
    loadv(0);
    __syncthreads();
  }

  for (int t = 1; t < 32; t++) {
    const int cur = t & 1;
    if (t + 1 < 32) stage(t + 1, cur ^ 1);
    // MFMA burst: PV(t-1) [reg-only] + QK(t); back-to-back into the matrix pipe
    f32x16 st[2];
    __builtin_amdgcn_s_setprio(1);
#pragma unroll
    for (int c = 0; c < 4; c++)
#pragma unroll
      for (int dt = 0; dt < 2; dt++)
        o[dt] = __builtin_amdgcn_mfma_f32_32x32x16_bf16(paq[c], vfr[dt][c], o[dt], 0, 0, 0);
    qk(cur, st);
    __builtin_amdgcn_s_setprio(0);
    // VALU phase overlaps matrix drain
    softpack(st);
    loadv(cur);
    __syncthreads();
  }
  // ---- epilogue: PV(31)
#pragma unroll
  for (int c = 0; c < 4; c++)
#pragma unroll
    for (int dt = 0; dt < 2; dt++)
      o[dt] = __builtin_amdgcn_mfma_f32_32x32x16_bf16(paq[c], vfr[dt][c], o[dt], 0, 0, 0);

  // full row sums: lanes l and l^32 both hold sum for s-col l31
  ls += __shfl_xor(ls, 32, 64);
  if (lhi == 0)
    lbuf[(size_t)bh * SEQ + s0 + l31] = ls;

  // epilogue: O row s = s0 + (r&3)+8*(r>>2)+4*lhi, col d = dt*32+l31
#pragma unroll
  for (int r = 0; r < 16; r++) {
    const int s_off = (r & 3) + 8 * (r >> 2) + 4 * lhi;
    float denom = __shfl(ls, s_off, 64);
    float inv = __builtin_amdgcn_rcpf(denom);
    const int s = s0 + s_off;
#pragma unroll
    for (int dt = 0; dt < 2; dt++) {
      float ov = o[dt][r] * inv;
      attn_bf[((size_t)s * BATCH + b) * EMB + h * HD + dt * 32 + l31] = f2bf(ov);
    }
  }
}

// ---------------------------------------------------------------- attention pass 2 (v8)
// v5 skeleton with 2 HEADS PER ITERATION: per t0-step both heads' K tiles are
// in LDS and the MFMA payload per barrier doubles (16 MFMA + 32 exp), halving
// the barrier count 64 -> 32. Staging identical to the proven v5 pattern
// (gload_lds, double-buffer, Q-pair staged at the hp boundary).
__global__ __launch_bounds__(256, 2) void attn2(
    const unsigned short* __restrict__ Qb,
    const unsigned short* __restrict__ Kb,
    const float* __restrict__ lbuf,
    float* __restrict__ avg_out) {
  const int b = blockIdx.z;
  const int s0 = blockIdx.y * 64;
  const int tc0 = blockIdx.x * 256;
  __shared__ int4 Qs[2][64][8];      // 16 KB  [head-of-pair]
  __shared__ int4 Ks[2][2][64][8];   // 32 KB  [dbuf][head-of-pair]
  __shared__ float lls[NH][64];      // 1/(NH*l)
  const int tid = threadIdx.x;
  const int wid = tid >> 6, lane = tid & 63;
  const int wm = wid >> 1, wn = wid & 1;
  const int lg = lane >> 4, lr = lane & 15;
  const int lr8 = lane >> 3;
  const int lc8 = (lane & 7) ^ lr8;

  for (int i = tid; i < NH * 64; i += 256) {
    int hh = i >> 6, r = i & 63;
    lls[hh][r] = 1.0f / ((float)NH * lbuf[(b * NH + hh) * SEQ + s0 + r]);
  }

  const size_t bh0 = (size_t)(b * NH) * SEQ;

  auto stageK = [&](const unsigned short* src, int buf, int hsel) {
#pragma unroll
    for (int i = 0; i < 2; i++) {
      const int rb = wid * 16 + i * 8;
      gload16(src + (size_t)(rb + lr8) * HD + lc8 * 8, &Ks[buf][hsel][rb][0]);
    }
  };
  auto stageQ = [&](const unsigned short* src, int hsel) {
#pragma unroll
    for (int i = 0; i < 2; i++) {
      const int rb = wid * 16 + i * 8;
      gload16(src + (size_t)(rb + lr8) * HD + lc8 * 8, &Qs[hsel][rb][0]);
    }
  };

  stageQ(Qb + (bh0 + s0) * HD, 0);
  stageQ(Qb + (bh0 + SEQ + s0) * HD, 1);
  stageK(Kb + (bh0 + tc0) * HD, 0, 0);
  stageK(Kb + (bh0 + SEQ + tc0) * HD, 0, 1);
  __syncthreads();

  const f32x4 fz4 = {};
  f32x4 avg[4][2][2] = {};

  for (int hp = 0; hp < NH / 2; hp++) {
    const int h0 = 2 * hp, h1 = h0 + 1;
    bf16x8 af[2][2][2];   // [head][mi][ks]
#pragma unroll
    for (int hh = 0; hh < 2; hh++)
#pragma unroll
      for (int mi = 0; mi < 2; mi++) {
        int r = wm * 32 + mi * 16 + lr;
#pragma unroll
        for (int ks = 0; ks < 2; ks++)
          af[hh][mi][ks] = *reinterpret_cast<const bf16x8*>(&Qs[hh][r][(ks * 4 + lg) ^ (r & 7)]);
      }
    float linv[2][2][4];
#pragma unroll
    for (int hh = 0; hh < 2; hh++)
#pragma unroll
      for (int mi = 0; mi < 2; mi++)
#pragma unroll
        for (int r = 0; r < 4; r++)
          linv[hh][mi][r] = lls[h0 + hh][wm * 32 + mi * 16 + lg * 4 + r];

    const unsigned short* Kg0 = Kb + (bh0 + (size_t)h0 * SEQ + tc0) * HD;
    const unsigned short* Kg1 = Kb + (bh0 + (size_t)h1 * SEQ + tc0) * HD;

    for (int t0 = 0; t0 < 4; t0++) {
      const int cur = t0 & 1;
      if (t0 < 3) {
        stageK(Kg0 + (size_t)(t0 + 1) * 64 * HD, cur ^ 1, 0);
        stageK(Kg1 + (size_t)(t0 + 1) * 64 * HD, cur ^ 1, 1);
      } else if (hp + 1 < NH / 2) {
        stageK(Kb + (bh0 + (size_t)(h0 + 2) * SEQ + tc0) * HD, cur ^ 1, 0);
        stageK(Kb + (bh0 + (size_t)(h1 + 2) * SEQ + tc0) * HD, cur ^ 1, 1);
        stageQ(Qb + (bh0 + (size_t)(h0 + 2) * SEQ + s0) * HD, 0);
        stageQ(Qb + (bh0 + (size_t)(h1 + 2) * SEQ + s0) * HD, 1);
      }
      f32x4 sacc[2][2][2];   // [head][mi][ni]
      __builtin_amdgcn_s_setprio(1);
#pragma unroll
      for (int hh = 0; hh < 2; hh++)
#pragma unroll
        for (int ks = 0; ks < 2; ks++) {
          bf16x8 bk[2];
#pragma unroll
          for (int ni = 0; ni < 2; ni++) {
            int rk = wn * 32 + ni * 16 + lr;
            bk[ni] = *reinterpret_cast<const bf16x8*>(&Ks[cur][hh][rk][(ks * 4 + lg) ^ (rk & 7)]);
          }
#pragma unroll
          for (int mi = 0; mi < 2; mi++)
#pragma unroll
            for (int ni = 0; ni < 2; ni++)
              sacc[hh][mi][ni] = __builtin_amdgcn_mfma_f32_16x16x32_bf16(
                  af[hh][mi][ks], bk[ni], ks == 0 ? fz4 : sacc[hh][mi][ni], 0, 0, 0);
        }
      __builtin_amdgcn_s_setprio(0);
#pragma unroll
      for (int hh = 0; hh < 2; hh++)
#pragma unroll
        for (int mi = 0; mi < 2; mi++)
#pragma unroll
          for (int ni = 0; ni < 2; ni++)
#pragma unroll
            for (int r = 0; r < 4; r++)
              avg[t0][mi][ni][r] += __builtin_amdgcn_exp2f(sacc[hh][mi][ni][r]) * linv[hh][mi][r];
      __syncthreads();
    }
  }

#pragma unroll
  for (int t0 = 0; t0 < 4; t0++)
#pragma unroll
    for (int mi = 0; mi < 2; mi++)
#pragma unroll
      for (int ni = 0; ni < 2; ni++)
#pragma unroll
        for (int r = 0; r < 4; r++) {
          int s = s0 + wm * 32 + mi * 16 + lg * 4 + r;
          int t = tc0 + t0 * 64 + wn * 32 + ni * 16 + lr;
          avg_out[((size_t)b * SEQ + s) * SEQ + t] = avg[t0][mi][ni][r];
        }
}

// ---------------------------------------------------------------- launch
extern "C" void kernel_launch(void* const* d_in, const int* in_sizes, int n_in,
                              void* d_out, int out_size, void* d_ws, size_t ws_size,
                              hipStream_t stream) {
  const float* x     = (const float*)d_in[0];   // [S,B,E]
  const float* w_qkv = (const float*)d_in[1];   // [3E,E]
  const float* b_qkv = (const float*)d_in[2];   // [3E]
  const float* w_out = (const float*)d_in[3];   // [E,E]
  const float* b_out = (const float*)d_in[4];   // [E]
  float* out = (float*)d_out;                         // [S,B,E] fp32
  float* avg = out + (size_t)SEQ * BATCH * EMB;       // [B,S,S] fp32

  char* ws = (char*)d_ws;
  size_t off = 0;
  unsigned short* x_bf    = (unsigned short*)(ws + off); off += (size_t)SEQ * BATCH * EMB * 2;       // 8 MB
  unsigned short* wqkv_bf = (unsigned short*)(ws + off); off += (size_t)3 * EMB * EMB * 2;           // 6 MB
  unsigned short* wout_bf = (unsigned short*)(ws + off); off += (size_t)EMB * EMB * 2;               // 2 MB
  unsigned short* Qbuf    = (unsigned short*)(ws + off); off += (size_t)BATCH * NH * SEQ * HD * 2;   // 8 MB
  unsigned short* Kbuf    = (unsigned short*)(ws + off); off += (size_t)BATCH * NH * SEQ * HD * 2;   // 8 MB
  unsigned short* VTbuf   = (unsigned short*)(ws + off); off += (size_t)BATCH * NH * HD * SEQ * 2;   // 8 MB
  unsigned short* attn_bf = (unsigned short*)(ws + off); off += (size_t)SEQ * BATCH * EMB * 2;       // 8 MB
  float*          lbuf    = (float*)(ws + off);          off += (size_t)BATCH * NH * SEQ * 4;        // 256 KB

  // 1) convert inputs to bf16 (single fused kernel)
  {
    const int na4 = SEQ * BATCH * EMB / 4;
    const int nb4 = 3 * EMB * EMB / 4;
    const int nc4 = EMB * EMB / 4;
    const int nblk = (na4 + nb4 + nc4 + 255) / 256;
    cvt3_f32_bf16<<<nblk, 256, 0, stream>>>(x, na4, w_qkv, nb4, w_out, nc4,
                                            x_bf, wqkv_bf, wout_bf);
  }

  // 2) QKV projection, scatter to Q (pre-scaled) / K [B][H][S][D] + V^T [B][H][D][S]
  gemm_bt<1><<<dim3(SEQ * BATCH / 128, 3 * EMB / 128), 256, 0, stream>>>(
      x_bf, wqkv_bf, b_qkv, nullptr, Qbuf, Kbuf, VTbuf, SEQ * BATCH, 3 * EMB, EMB);

  // 3) attention core (v7: 2-deep PV/QK pipeline)
  attn1<<<512, 256, 0, stream>>>(Qbuf, Kbuf, VTbuf, attn_bf, lbuf);

  // 4) attention average over heads (v8: 2 heads per barrier)
  attn2<<<dim3(SEQ / 256, SEQ / 64, BATCH), 256, 0, stream>>>(Qbuf, Kbuf, lbuf, avg);

  // 5) output projection -> d_out
  gemm_bt<0><<<dim3(SEQ * BATCH / 128, EMB / 128), 256, 0, stream>>>(
      attn_bf, wout_bf, b_out, out, nullptr, nullptr, nullptr, SEQ * BATCH, EMB, EMB);
}

// Round 12
// 144.949 us; speedup vs baseline: 1.6582x; 1.0008x over previous
//
#include <hip/hip_runtime.h>

// Problem constants (S, B, E, H) = (2048, 2, 1024, 16), D = 64
#define SEQ   2048
#define BATCH 2
#define NH    16
#define HD    64
#define EMB   1024

// Q is pre-scaled by log2(e)/8 at the QKV-projection epilogue, so both
// attention kernels compute exp(score/8) as exp2(S) with no per-element mul.
#define QSCALE 0.18033688011112042f

using bf16x8 = __attribute__((ext_vector_type(8))) short;  // 8 bf16 (4 VGPRs)
using f32x4  = __attribute__((ext_vector_type(4))) float;
using f32x16 = __attribute__((ext_vector_type(16))) float;

__device__ __forceinline__ unsigned short f2bf(float f) {
  unsigned int u = __float_as_uint(f);
  u += 0x7FFFu + ((u >> 16) & 1u);          // RNE
  return (unsigned short)(u >> 16);
}
__device__ __forceinline__ unsigned pk_bf16(float lo, float hi) {
  unsigned r;
  asm("v_cvt_pk_bf16_f32 %0, %1, %2" : "=v"(r) : "v"(lo), "v"(hi));
  return r;
}
// async global->LDS, 16B per lane; LDS dest = uniform base + lane*16
__device__ __forceinline__ void gload16(const void* g, void* l) {
  __builtin_amdgcn_global_load_lds(
      (const __attribute__((address_space(1))) unsigned int*)g,
      (__attribute__((address_space(3))) unsigned int*)l, 16, 0, 0);
}

// ---------------------------------------------------------------- cvt f32->bf16 (fused x, w_qkv, w_out)
__global__ __launch_bounds__(256) void cvt3_f32_bf16(
    const float* __restrict__ a, int na4,
    const float* __restrict__ b, int nb4,
    const float* __restrict__ c, int nc4,
    unsigned short* __restrict__ oa,
    unsigned short* __restrict__ ob,
    unsigned short* __restrict__ oc) {
  int i = blockIdx.x * 256 + threadIdx.x;
  const float* src;
  unsigned short* dst;
  int j = i;
  if (j < na4) { src = a; dst = oa; }
  else if ((j -= na4) < nb4) { src = b; dst = ob; }
  else { j -= nb4; if (j >= nc4) return; src = c; dst = oc; }
  float4 v = reinterpret_cast<const float4*>(src)[j];
  ushort4 o;
  o.x = f2bf(v.x); o.y = f2bf(v.y); o.z = f2bf(v.z); o.w = f2bf(v.w);
  reinterpret_cast<ushort4*>(dst)[j] = o;
}

// ---------------------------------------------------------------- GEMM C = A * B^T (+bias)
// A[M][K] bf16, B[N][K] bf16, fp32 accumulate. 128x128 tile, BK=64, 4 waves (2x2).
// Staging via global_load_lds dwordx4: linear LDS dest, pre-swizzled global src
// (slot [r][cc] holds global chunk cc^(r&7); readers use [r][j^(r&7)]).
// 16-row fragment reads -> (r&7) swizzle is 2-way (free) here.
// EPI==0: C fp32 row-major [M][N]
// EPI==1: scatter QKV -> Q (x QSCALE) / K bf16 [B][H][S][D], V -> V^T bf16 [B][H][D][S]
template <int EPI>
__global__ __launch_bounds__(256) void gemm_bt(
    const unsigned short* __restrict__ A,
    const unsigned short* __restrict__ B,
    const float* __restrict__ bias,
    float* __restrict__ Cf,
    unsigned short* __restrict__ Qb,
    unsigned short* __restrict__ Kb,
    unsigned short* __restrict__ VTb,
    int M, int N, int K) {
  __shared__ int4 As[128][8];
  __shared__ int4 Bs[128][8];
  const int tid = threadIdx.x;
  const int wid = tid >> 6, lane = tid & 63;
  const int wm = wid >> 1, wn = wid & 1;
  const int lg = lane >> 4, lr = lane & 15;
  const int lr8 = lane >> 3;                 // staging row-within-8
  const int lc8 = (lane & 7) ^ lr8;          // pre-swizzled source chunk
  const int row0 = blockIdx.x * 128, col0 = blockIdx.y * 128;
  f32x4 acc[4][4] = {};
  for (int k0 = 0; k0 < K; k0 += 64) {
#pragma unroll
    for (int i = 0; i < 4; i++) {
      const int rb = wid * 32 + i * 8;
      gload16(&A[(size_t)(row0 + rb + lr8) * K + k0 + lc8 * 8], &As[rb][0]);
      gload16(&B[(size_t)(col0 + rb + lr8) * K + k0 + lc8 * 8], &Bs[rb][0]);
    }
    __syncthreads();
#pragma unroll
    for (int ks = 0; ks < 2; ks++) {
      bf16x8 af[4], bfr[4];
#pragma unroll
      for (int mi = 0; mi < 4; mi++) {
        int r = wm * 64 + mi * 16 + lr;
        af[mi] = *reinterpret_cast<const bf16x8*>(&As[r][(ks * 4 + lg) ^ (r & 7)]);
      }
#pragma unroll
      for (int ni = 0; ni < 4; ni++) {
        int r = wn * 64 + ni * 16 + lr;
        bfr[ni] = *reinterpret_cast<const bf16x8*>(&Bs[r][(ks * 4 + lg) ^ (r & 7)]);
      }
#pragma unroll
      for (int mi = 0; mi < 4; mi++)
#pragma unroll
        for (int ni = 0; ni < 4; ni++)
          acc[mi][ni] = __builtin_amdgcn_mfma_f32_16x16x32_bf16(af[mi], bfr[ni], acc[mi][ni], 0, 0, 0);
    }
    __syncthreads();
  }
  // epilogue: C/D layout col=lane&15, row=(lane>>4)*4+r  [m89-verified]
#pragma unroll
  for (int mi = 0; mi < 4; mi++)
#pragma unroll
    for (int ni = 0; ni < 4; ni++) {
      const int row_b = row0 + wm * 64 + mi * 16 + lg * 4;   // even
      const int col = col0 + wn * 64 + ni * 16 + lr;
      const float bs = bias[col];
      float v0 = acc[mi][ni][0] + bs;
      float v1 = acc[mi][ni][1] + bs;
      float v2 = acc[mi][ni][2] + bs;
      float v3 = acc[mi][ni][3] + bs;
      if (EPI == 0) {
        Cf[(size_t)(row_b + 0) * N + col] = v0;
        Cf[(size_t)(row_b + 1) * N + col] = v1;
        Cf[(size_t)(row_b + 2) * N + col] = v2;
        Cf[(size_t)(row_b + 3) * N + col] = v3;
      } else {
        const int which = col >> 10, rr = col & 1023;
        const int hh = rr >> 6, d = rr & 63;
        if (which == 2) {
          // V^T [b][h][d][s]; rows row_b+r = s*2+b -> b=r&1, s=s0+(r>>1)
          const int s0 = row_b >> 1;
          ushort2 p0; p0.x = f2bf(v0); p0.y = f2bf(v2);   // b=0: s0, s0+1
          ushort2 p1; p1.x = f2bf(v1); p1.y = f2bf(v3);   // b=1
          *reinterpret_cast<ushort2*>(&VTb[((size_t)((0 * NH + hh) * HD + d)) * SEQ + s0]) = p0;
          *reinterpret_cast<ushort2*>(&VTb[((size_t)((1 * NH + hh) * HD + d)) * SEQ + s0]) = p1;
        } else {
          unsigned short* dst = which == 0 ? Qb : Kb;
          const float sc = (which == 0) ? QSCALE : 1.0f;
          float vv[4] = {v0 * sc, v1 * sc, v2 * sc, v3 * sc};
#pragma unroll
          for (int r = 0; r < 4; r++) {
            int s = (row_b + r) >> 1, bb = r & 1;
            dst[(size_t)((bb * NH + hh) * SEQ + s) * HD + d] = f2bf(vv[r]);
          }
        }
      }
    }
}

// ---------------------------------------------------------------- attention pass 1 (v8)
// v7 pipeline + two fixes:
//  (1) LDS swizzle widened to chunk ^ ((row>>2)&7): conflict-free for the
//      32-row fragment reads of the 32x32 MFMA (old (row&7) was 4-way:
//      4.19M SQ_LDS_BANK_CONFLICT measured). Stage source pre-swizzle matches.
//  (2) row-sum via ones-vector MFMA (o_sum = P x 1), replacing 32 serial VALU
//      adds + end shfl; denominator lands in o's exact register layout.
__global__ __launch_bounds__(256, 2) void attn1(
    const unsigned short* __restrict__ Qb,
    const unsigned short* __restrict__ Kb,
    const unsigned short* __restrict__ VTb,
    unsigned short* __restrict__ attn_bf,
    float* __restrict__ lbuf) {
  __shared__ int4 Kt[2][64][8];   // [t-row][chunk]; slot cc holds chunk cc^((row>>2)&7)
  __shared__ int4 Vt[2][64][8];   // [d-row][t chunks]
  const int tid = threadIdx.x;
  const int wid = tid >> 6, lane = tid & 63;
  const int l31 = lane & 31, lhi = lane >> 5;
  const int lr8 = lane >> 3;
  // XCD-aware remap: XCD x gets bh groups [4x, 4x+4) -> each K/V panel on one XCD.
  const int L = blockIdx.x;
  const int v = (L & 7) * 64 + (L >> 3);
  const int bh = v >> 4, stile = v & 15;
  const int b = bh >> 4, h = bh & 15;
  const int s0 = stile * 128 + wid * 32;
  const unsigned short* Qg = Qb + (size_t)bh * SEQ * HD;
  const unsigned short* Kg = Kb + (size_t)bh * SEQ * HD;
  const unsigned short* VTg = VTb + (size_t)bh * HD * SEQ;

  // Q fragments (B-operand): s = s0 + l31, d = ks*16 + lhi*8 + j
  bf16x8 qf[4];
#pragma unroll
  for (int ks = 0; ks < 4; ks++)
    qf[ks] = *reinterpret_cast<const bf16x8*>(Qg + (size_t)(s0 + l31) * HD + ks * 16 + lhi * 8);

  // stage: slot cc of row r holds global chunk cc ^ ((r>>2)&7).
  // gload16 writes lanes linearly: row = rb + (lane>>3), slot = lane&7,
  // so source chunk = (lane&7) ^ (((rb>>2) + lhi) & 7)   [(rb+lr8)>>2 = rb>>2 + lhi]
  auto stage = [&](int tg, int buf) {
#pragma unroll
    for (int i = 0; i < 2; i++) {
      const int rb = wid * 16 + i * 8;
      const int lc = (lane & 7) ^ (((rb >> 2) + lhi) & 7);
      gload16(Kg + (size_t)(tg * 64 + rb + lr8) * HD + lc * 8, &Kt[buf][rb][0]);
      gload16(VTg + (size_t)(rb + lr8) * SEQ + tg * 64 + lc * 8, &Vt[buf][rb][0]);
    }
  };
  // read swizzle for fragment rows (row = ti*32 + l31): (row>>2)&7 = l31>>2
  const int swv = l31 >> 2;

  const f32x16 fz = {};   // hoisted zero accumulator
  f32x16 o[2] = {};       // [dt]: O rows s, col d = dt*32 + l31
  f32x16 osum = {};       // row sums via ones-MFMA (same layout as o)
  const short one_bf = (short)0x3F80;
  const bf16x8 vone = {one_bf, one_bf, one_bf, one_bf, one_bf, one_bf, one_bf, one_bf};
  bf16x8 paq[4];          // packed P A-fragments of previous tile
  bf16x8 vfr[2][4];       // V^T B-fragments of previous tile

  // QK helper: S^T = K * Q from Kt[cur]; lane owns s-column l31
  auto qk = [&](int cur, f32x16 st[2]) {
#pragma unroll
    for (int ti = 0; ti < 2; ti++) {
      const int row = ti * 32 + l31;
      bf16x8 kf = *reinterpret_cast<const bf16x8*>(&Kt[cur][row][lhi ^ swv]);
      st[ti] = __builtin_amdgcn_mfma_f32_32x32x16_bf16(kf, qf[0], fz, 0, 0, 0);
    }
#pragma unroll
    for (int ks = 1; ks < 4; ks++)
#pragma unroll
      for (int ti = 0; ti < 2; ti++) {
        const int row = ti * 32 + l31;
        bf16x8 kf = *reinterpret_cast<const bf16x8*>(&Kt[cur][row][(ks * 2 + lhi) ^ swv]);
        st[ti] = __builtin_amdgcn_mfma_f32_32x32x16_bf16(kf, qf[ks], st[ti], 0, 0, 0);
      }
  };
  // exp + in-register pack -> paq (row sums now via ones-MFMA in the PV burst)
  auto softpack = [&](const f32x16 st[2]) {
    float p[32];
#pragma unroll
    for (int ti = 0; ti < 2; ti++)
#pragma unroll
      for (int r = 0; r < 16; r++)
        p[ti * 16 + r] = __builtin_amdgcn_exp2f(st[ti][r]);
#pragma unroll
    for (int c = 0; c < 4; c++) {
      const int ti = c >> 1, cc = c & 1;
      const int pb = ti * 16 + cc * 8;
      unsigned w0 = pk_bf16(p[pb + 0], p[pb + 1]);
      unsigned w1 = pk_bf16(p[pb + 2], p[pb + 3]);
      unsigned w2 = pk_bf16(p[pb + 4], p[pb + 5]);
      unsigned w3 = pk_bf16(p[pb + 6], p[pb + 7]);
      // one swap fills two A-frag words (lhi ? {x2,w2} : {w0,x0})
      asm volatile("v_permlane32_swap_b32 %0, %1" : "+v"(w0), "+v"(w2));
      asm volatile("v_permlane32_swap_b32 %0, %1" : "+v"(w1), "+v"(w3));
      union { unsigned u[4]; bf16x8 v; } pa;
      pa.u[0] = w0; pa.u[1] = w1; pa.u[2] = w2; pa.u[3] = w3;
      paq[c] = pa.v;
    }
  };
  auto loadv = [&](int cur) {
#pragma unroll
    for (int dt = 0; dt < 2; dt++)
#pragma unroll
      for (int c = 0; c < 4; c++) {
        const int row = dt * 32 + l31;
        vfr[dt][c] = *reinterpret_cast<const bf16x8*>(&Vt[cur][row][(c * 2 + lhi) ^ swv]);
      }
  };

  stage(0, 0);
  __syncthreads();

  // ---- prologue t = 0: no PV yet
  {
    stage(1, 1);
    f32x16 st[2];
    __builtin_amdgcn_s_setprio(1);
    qk(0, st);
    __builtin_amdgcn_s_setprio(0);
    softpack(st);
    loadv(0);
    __syncthreads();
  }

  for (int t = 1; t < 32; t++) {
    const int cur = t & 1;
    if (t + 1 < 32) stage(t + 1, cur ^ 1);
    // MFMA burst: PV(t-1) + row-sum(t-1) [reg-only] + QK(t)
    f32x16 st[2];
    __builtin_amdgcn_s_setprio(1);
#pragma unroll
    for (int c = 0; c < 4; c++) {
#pragma unroll
      for (int dt = 0; dt < 2; dt++)
        o[dt] = __builtin_amdgcn_mfma_f32_32x32x16_bf16(paq[c], vfr[dt][c], o[dt], 0, 0, 0);
      osum = __builtin_amdgcn_mfma_f32_32x32x16_bf16(paq[c], vone, osum, 0, 0, 0);
    }
    qk(cur, st);
    __builtin_amdgcn_s_setprio(0);
    // VALU phase overlaps matrix drain
    softpack(st);
    loadv(cur);
    __syncthreads();
  }
  // ---- epilogue: PV(31) + row-sum(31)
#pragma unroll
  for (int c = 0; c < 4; c++) {
#pragma unroll
    for (int dt = 0; dt < 2; dt++)
      o[dt] = __builtin_amdgcn_mfma_f32_32x32x16_bf16(paq[c], vfr[dt][c], o[dt], 0, 0, 0);
    osum = __builtin_amdgcn_mfma_f32_32x32x16_bf16(paq[c], vone, osum, 0, 0, 0);
  }

  // lbuf: osum[r] holds Sum_t P for row s0 + (r&3)+8*(r>>2)+4*lhi (all l31 copies)
  if (l31 == 0) {
#pragma unroll
    for (int r = 0; r < 16; r++)
      lbuf[(size_t)bh * SEQ + s0 + (r & 3) + 8 * (r >> 2) + 4 * lhi] = osum[r];
  }

  // epilogue: O row s = s0 + (r&3)+8*(r>>2)+4*lhi, col d = dt*32+l31
#pragma unroll
  for (int r = 0; r < 16; r++) {
    float inv = __builtin_amdgcn_rcpf(osum[r]);
    const int s = s0 + (r & 3) + 8 * (r >> 2) + 4 * lhi;
#pragma unroll
    for (int dt = 0; dt < 2; dt++) {
      float ov = o[dt][r] * inv;
      attn_bf[((size_t)s * BATCH + b) * EMB + h * HD + dt * 32 + l31] = f2bf(ov);
    }
  }
}

// ---------------------------------------------------------------- attention pass 2 (v8)
// v5 skeleton with 2 HEADS PER ITERATION: per t0-step both heads' K tiles are
// in LDS and the MFMA payload per barrier doubles (16 MFMA + 32 exp), halving
// the barrier count 64 -> 32. Staging identical to the proven v5 pattern
// (gload_lds, double-buffer, Q-pair staged at the hp boundary).
__global__ __launch_bounds__(256, 2) void attn2(
    const unsigned short* __restrict__ Qb,
    const unsigned short* __restrict__ Kb,
    const float* __restrict__ lbuf,
    float* __restrict__ avg_out) {
  const int b = blockIdx.z;
  const int s0 = blockIdx.y * 64;
  const int tc0 = blockIdx.x * 256;
  __shared__ int4 Qs[2][64][8];      // 16 KB  [head-of-pair]
  __shared__ int4 Ks[2][2][64][8];   // 32 KB  [dbuf][head-of-pair]
  __shared__ float lls[NH][64];      // 1/(NH*l)
  const int tid = threadIdx.x;
  const int wid = tid >> 6, lane = tid & 63;
  const int wm = wid >> 1, wn = wid & 1;
  const int lg = lane >> 4, lr = lane & 15;
  const int lr8 = lane >> 3;
  const int lc8 = (lane & 7) ^ lr8;

  for (int i = tid; i < NH * 64; i += 256) {
    int hh = i >> 6, r = i & 63;
    lls[hh][r] = 1.0f / ((float)NH * lbuf[(b * NH + hh) * SEQ + s0 + r]);
  }

  const size_t bh0 = (size_t)(b * NH) * SEQ;

  auto stageK = [&](const unsigned short* src, int buf, int hsel) {
#pragma unroll
    for (int i = 0; i < 2; i++) {
      const int rb = wid * 16 + i * 8;
      gload16(src + (size_t)(rb + lr8) * HD + lc8 * 8, &Ks[buf][hsel][rb][0]);
    }
  };
  auto stageQ = [&](const unsigned short* src, int hsel) {
#pragma unroll
    for (int i = 0; i < 2; i++) {
      const int rb = wid * 16 + i * 8;
      gload16(src + (size_t)(rb + lr8) * HD + lc8 * 8, &Qs[hsel][rb][0]);
    }
  };

  stageQ(Qb + (bh0 + s0) * HD, 0);
  stageQ(Qb + (bh0 + SEQ + s0) * HD, 1);
  stageK(Kb + (bh0 + tc0) * HD, 0, 0);
  stageK(Kb + (bh0 + SEQ + tc0) * HD, 0, 1);
  __syncthreads();

  const f32x4 fz4 = {};
  f32x4 avg[4][2][2] = {};

  for (int hp = 0; hp < NH / 2; hp++) {
    const int h0 = 2 * hp, h1 = h0 + 1;
    bf16x8 af[2][2][2];   // [head][mi][ks]
#pragma unroll
    for (int hh = 0; hh < 2; hh++)
#pragma unroll
      for (int mi = 0; mi < 2; mi++) {
        int r = wm * 32 + mi * 16 + lr;
#pragma unroll
        for (int ks = 0; ks < 2; ks++)
          af[hh][mi][ks] = *reinterpret_cast<const bf16x8*>(&Qs[hh][r][(ks * 4 + lg) ^ (r & 7)]);
      }
    float linv[2][2][4];
#pragma unroll
    for (int hh = 0; hh < 2; hh++)
#pragma unroll
      for (int mi = 0; mi < 2; mi++)
#pragma unroll
        for (int r = 0; r < 4; r++)
          linv[hh][mi][r] = lls[h0 + hh][wm * 32 + mi * 16 + lg * 4 + r];

    const unsigned short* Kg0 = Kb + (bh0 + (size_t)h0 * SEQ + tc0) * HD;
    const unsigned short* Kg1 = Kb + (bh0 + (size_t)h1 * SEQ + tc0) * HD;

    for (int t0 = 0; t0 < 4; t0++) {
      const int cur = t0 & 1;
      if (t0 < 3) {
        stageK(Kg0 + (size_t)(t0 + 1) * 64 * HD, cur ^ 1, 0);
        stageK(Kg1 + (size_t)(t0 + 1) * 64 * HD, cur ^ 1, 1);
      } else if (hp + 1 < NH / 2) {
        stageK(Kb + (bh0 + (size_t)(h0 + 2) * SEQ + tc0) * HD, cur ^ 1, 0);
        stageK(Kb + (bh0 + (size_t)(h1 + 2) * SEQ + tc0) * HD, cur ^ 1, 1);
        stageQ(Qb + (bh0 + (size_t)(h0 + 2) * SEQ + s0) * HD, 0);
        stageQ(Qb + (bh0 + (size_t)(h1 + 2) * SEQ + s0) * HD, 1);
      }
      f32x4 sacc[2][2][2];   // [head][mi][ni]
      __builtin_amdgcn_s_setprio(1);
#pragma unroll
      for (int hh = 0; hh < 2; hh++)
#pragma unroll
        for (int ks = 0; ks < 2; ks++) {
          bf16x8 bk[2];
#pragma unroll
          for (int ni = 0; ni < 2; ni++) {
            int rk = wn * 32 + ni * 16 + lr;
            bk[ni] = *reinterpret_cast<const bf16x8*>(&Ks[cur][hh][rk][(ks * 4 + lg) ^ (rk & 7)]);
          }
#pragma unroll
          for (int mi = 0; mi < 2; mi++)
#pragma unroll
            for (int ni = 0; ni < 2; ni++)
              sacc[hh][mi][ni] = __builtin_amdgcn_mfma_f32_16x16x32_bf16(
                  af[hh][mi][ks], bk[ni], ks == 0 ? fz4 : sacc[hh][mi][ni], 0, 0, 0);
        }
      __builtin_amdgcn_s_setprio(0);
#pragma unroll
      for (int hh = 0; hh < 2; hh++)
#pragma unroll
        for (int mi = 0; mi < 2; mi++)
#pragma unroll
          for (int ni = 0; ni < 2; ni++)
#pragma unroll
            for (int r = 0; r < 4; r++)
              avg[t0][mi][ni][r] += __builtin_amdgcn_exp2f(sacc[hh][mi][ni][r]) * linv[hh][mi][r];
      __syncthreads();
    }
  }

#pragma unroll
  for (int t0 = 0; t0 < 4; t0++)
#pragma unroll
    for (int mi = 0; mi < 2; mi++)
#pragma unroll
      for (int ni = 0; ni < 2; ni++)
#pragma unroll
        for (int r = 0; r < 4; r++) {
          int s = s0 + wm * 32 + mi * 16 + lg * 4 + r;
          int t = tc0 + t0 * 64 + wn * 32 + ni * 16 + lr;
          avg_out[((size_t)b * SEQ + s) * SEQ + t] = avg[t0][mi][ni][r];
        }
}

// ---------------------------------------------------------------- launch
extern "C" void kernel_launch(void* const* d_in, const int* in_sizes, int n_in,
                              void* d_out, int out_size, void* d_ws, size_t ws_size,
                              hipStream_t stream) {
  const float* x     = (const float*)d_in[0];   // [S,B,E]
  const float* w_qkv = (const float*)d_in[1];   // [3E,E]
  const float* b_qkv = (const float*)d_in[2];   // [3E]
  const float* w_out = (const float*)d_in[3];   // [E,E]
  const float* b_out = (const float*)d_in[4];   // [E]
  float* out = (float*)d_out;                         // [S,B,E] fp32
  float* avg = out + (size_t)SEQ * BATCH * EMB;       // [B,S,S] fp32

  char* ws = (char*)d_ws;
  size_t off = 0;
  unsigned short* x_bf    = (unsigned short*)(ws + off); off += (size_t)SEQ * BATCH * EMB * 2;       // 8 MB
  unsigned short* wqkv_bf = (unsigned short*)(ws + off); off += (size_t)3 * EMB * EMB * 2;           // 6 MB
  unsigned short* wout_bf = (unsigned short*)(ws + off); off += (size_t)EMB * EMB * 2;               // 2 MB
  unsigned short* Qbuf    = (unsigned short*)(ws + off); off += (size_t)BATCH * NH * SEQ * HD * 2;   // 8 MB
  unsigned short* Kbuf    = (unsigned short*)(ws + off); off += (size_t)BATCH * NH * SEQ * HD * 2;   // 8 MB
  unsigned short* VTbuf   = (unsigned short*)(ws + off); off += (size_t)BATCH * NH * HD * SEQ * 2;   // 8 MB
  unsigned short* attn_bf = (unsigned short*)(ws + off); off += (size_t)SEQ * BATCH * EMB * 2;       // 8 MB
  float*          lbuf    = (float*)(ws + off);          off += (size_t)BATCH * NH * SEQ * 4;        // 256 KB

  // 1) convert inputs to bf16 (single fused kernel)
  {
    const int na4 = SEQ * BATCH * EMB / 4;
    const int nb4 = 3 * EMB * EMB / 4;
    const int nc4 = EMB * EMB / 4;
    const int nblk = (na4 + nb4 + nc4 + 255) / 256;
    cvt3_f32_bf16<<<nblk, 256, 0, stream>>>(x, na4, w_qkv, nb4, w_out, nc4,
                                            x_bf, wqkv_bf, wout_bf);
  }

  // 2) QKV projection, scatter to Q (pre-scaled) / K [B][H][S][D] + V^T [B][H][D][S]
  gemm_bt<1><<<dim3(SEQ * BATCH / 128, 3 * EMB / 128), 256, 0, stream>>>(
      x_bf, wqkv_bf, b_qkv, nullptr, Qbuf, Kbuf, VTbuf, SEQ * BATCH, 3 * EMB, EMB);

  // 3) attention core (v8: conflict-free swizzle + ones-MFMA row sums)
  attn1<<<512, 256, 0, stream>>>(Qbuf, Kbuf, VTbuf, attn_bf, lbuf);

  // 4) attention average over heads (v8: 2 heads per barrier)
  attn2<<<dim3(SEQ / 256, SEQ / 64, BATCH), 256, 0, stream>>>(Qbuf, Kbuf, lbuf, avg);

  // 5) output projection -> d_out
  gemm_bt<0><<<dim3(SEQ * BATCH / 128, EMB / 128), 256, 0, stream>>>(
      attn_bf, wout_bf, b_out, out, nullptr, nullptr, nullptr, SEQ * BATCH, EMB, EMB);
}